// Round 5
// baseline (1480.185 us; speedup 1.0000x reference)
//
#include <hip/hip_runtime.h>
#include <hip/hip_bf16.h>

#define HD 128
#define ED 16
#define TD 32

typedef __attribute__((ext_vector_type(8))) short short8;
typedef __attribute__((ext_vector_type(4))) float float4v;

__device__ __forceinline__ float rcpf(float x){ return __builtin_amdgcn_rcpf(x); }
__device__ __forceinline__ float siluf(float v){ return v * rcpf(1.0f + __expf(-v)); }

// bf16 pack/unpack helpers
__device__ __forceinline__ unsigned int bfbits(float x){          // RTNE
  unsigned int a = __float_as_uint(x);
  return (a + 0x7fffu + ((a >> 16) & 1u)) >> 16;
}
__device__ __forceinline__ unsigned int packbf(float lo, float hi){  // RTNE pair
  return (bfbits(lo) & 0xffffu) | (bfbits(hi) << 16);
}
// 1-op truncation pack via v_perm_b32: [lo.b2, lo.b3, hi.b2, hi.b3]
__device__ __forceinline__ unsigned int packtrunc(float lo, float hi){
  return __builtin_amdgcn_perm(__float_as_uint(hi), __float_as_uint(lo), 0x07060302u);
}
__device__ __forceinline__ float unplo(unsigned int w){ return __uint_as_float(w << 16); }
__device__ __forceinline__ float unphi(unsigned int w){ return __uint_as_float(w & 0xffff0000u); }
__device__ __forceinline__ unsigned short f2b(float x){ return (unsigned short)bfbits(x); }

__device__ __forceinline__ void unp8(uint4 u, float* f){
  f[0]=unplo(u.x); f[1]=unphi(u.x); f[2]=unplo(u.y); f[3]=unphi(u.y);
  f[4]=unplo(u.z); f[5]=unphi(u.z); f[6]=unplo(u.w); f[7]=unphi(u.w);
}

__device__ __forceinline__ void atomAddF(float* p, float v){
  unsafeAtomicAdd(p, v);  // HW global_atomic_add_f32 on gfx950
}

// packed bf16 atomic add: one instruction adds 2 bf16 lanes-worth
__device__ __forceinline__ void atomAddBF2(unsigned short* p, unsigned int packed){
  asm volatile("global_atomic_pk_add_bf16 %0, %1, off"
               :: "v"((unsigned long long)(uintptr_t)p), "v"(packed) : "memory");
}

// ---------------------------------------------------------------------------
// Kernel 0: fp32 -> bf16 (RTNE) stream convert, 8 elems/thread-iter.
// ---------------------------------------------------------------------------
__global__ void __launch_bounds__(256) k_cvt(
    const float* __restrict__ src, unsigned short* __restrict__ dst, int n8)
{
  for (int i = blockIdx.x * 256 + threadIdx.x; i < n8; i += gridDim.x * 256){
    float4 v0 = *(const float4*)(src + (size_t)i * 8);
    float4 v1 = *(const float4*)(src + (size_t)i * 8 + 4);
    uint4 o;
    o.x = packbf(v0.x, v0.y); o.y = packbf(v0.z, v0.w);
    o.z = packbf(v1.x, v1.y); o.w = packbf(v1.z, v1.w);
    *(uint4*)(dst + (size_t)i * 8) = o;
  }
}

// ---------------------------------------------------------------------------
// Weight prep: bf16-transposed W2 tables + tail-B tables, read from global
// (L1/L2-broadcast) by the edge kernels so LDS stays small -> 4 blocks/CU.
// ---------------------------------------------------------------------------
__global__ void __launch_bounds__(256) k_prepw(
    const float* __restrict__ We_w2, const float* __restrict__ Wx_w2,
    const float* __restrict__ We_w1, const float* __restrict__ Wx_w1,
    unsigned short* __restrict__ W2Te, unsigned short* __restrict__ W2Tx,
    unsigned short* __restrict__ BtlE, unsigned short* __restrict__ BtlX)
{
  const int i0 = blockIdx.x * 256 + threadIdx.x, st = gridDim.x * 256;
  for (int i = i0; i < 128 * 128; i += st){
    int col = i >> 7, k = i & 127;
    W2Te[col * 128 + k] = f2b(We_w2[k * 128 + col]);
    W2Tx[col * 128 + k] = f2b(Wx_w2[k * 128 + col]);
  }
  for (int i = i0; i < 128 * 24; i += st){
    int col = i / 24, k = i % 24;
    float wv = (k < 16) ? We_w1[(257 + k) * 128 + col]
             : (k == 16 ? We_w1[256 * 128 + col] : 0.f);
    BtlE[col * 24 + k] = f2b(wv);
  }
  for (int i = i0; i < 128 * 16; i += st){
    int col = i >> 4, k = i & 15;
    BtlX[col * 16 + k] = f2b(Wx_w1[(256 + k) * 128 + col]);
  }
}

// ---------------------------------------------------------------------------
// Sort-by-dst preprocessing: hist -> scan -> scatter.
// k_scatter also hoists ALL per-edge scalar work: daux = (dx,dy,dz,dist),
// eaS = edge_attr in sorted order as bf16 (kills perm gathers in edge kernels).
// ---------------------------------------------------------------------------
__global__ void __launch_bounds__(256) k_hist(
    const int* __restrict__ ei, int* __restrict__ cnt, int E)
{
  for (int e = blockIdx.x * 256 + threadIdx.x; e < E; e += gridDim.x * 256)
    atomicAdd(&cnt[ei[E + e]], 1);
}

__global__ void __launch_bounds__(1024) k_scan(
    const int* __restrict__ cnt, int* __restrict__ off, int n)
{
  const int tid = threadIdx.x, lane = tid & 63, wv = tid >> 6;  // 16 waves
  __shared__ int wsum[16];
  __shared__ int carryS;
  if (tid == 0) carryS = 0;
  __syncthreads();
  const int CH = 1024 * 8;
  for (int base = 0; base < n; base += CH){
    const int idx0 = base + tid * 8;
    int v[8];
    #pragma unroll
    for (int j = 0; j < 8; ++j){ int i = idx0 + j; v[j] = (i < n) ? cnt[i] : 0; }
    #pragma unroll
    for (int j = 1; j < 8; ++j) v[j] += v[j - 1];   // local inclusive
    const int tot = v[7];
    int sc = tot;                                    // wave inclusive scan
    #pragma unroll
    for (int d = 1; d < 64; d <<= 1){ int t = __shfl_up(sc, d); if (lane >= d) sc += t; }
    if (lane == 63) wsum[wv] = sc;
    __syncthreads();
    if (tid < 16){
      int s = wsum[tid];
      #pragma unroll
      for (int d = 1; d < 16; d <<= 1){ int t = __shfl_up(s, d); if (tid >= d) s += t; }
      wsum[tid] = s;
    }
    __syncthreads();
    const int base_excl = carryS + (wv > 0 ? wsum[wv - 1] : 0) + (sc - tot);
    #pragma unroll
    for (int j = 0; j < 8; ++j){
      int i = idx0 + j;
      if (i < n) off[i] = base_excl + (j > 0 ? v[j - 1] : 0);
    }
    __syncthreads();
    if (tid == 0) carryS += wsum[15];
    __syncthreads();
  }
}

__global__ void __launch_bounds__(256) k_scatter(
    const int* __restrict__ ei, const float* __restrict__ x,
    const float* __restrict__ ea, int* __restrict__ off,
    int* __restrict__ ss, int* __restrict__ ddv,
    float4* __restrict__ daux, unsigned short* __restrict__ eaS, int E)
{
  for (int e = blockIdx.x * 256 + threadIdx.x; e < E; e += gridDim.x * 256){
    int s = ei[e], d = ei[E + e];
    int pos = atomicAdd(&off[d], 1);
    ss[pos] = s; ddv[pos] = d;
    float dx = x[s * 3 + 0] - x[d * 3 + 0];
    float dy = x[s * 3 + 1] - x[d * 3 + 1];
    float dz = x[s * 3 + 2] - x[d * 3 + 2];
    float4 da; da.x = dx; da.y = dy; da.z = dz; da.w = dx*dx + dy*dy + dz*dz;
    daux[pos] = da;
    const float4* e4 = (const float4*)(ea + (size_t)e * ED);
    float4 a = e4[0], b = e4[1], c = e4[2], dd = e4[3];
    uint4 o1, o2;
    o1.x = packtrunc(a.x, a.y); o1.y = packtrunc(a.z, a.w);
    o1.z = packtrunc(b.x, b.y); o1.w = packtrunc(b.z, b.w);
    o2.x = packtrunc(c.x, c.y); o2.y = packtrunc(c.z, c.w);
    o2.z = packtrunc(dd.x, dd.y); o2.w = packtrunc(dd.z, dd.w);
    *(uint4*)(eaS + (size_t)pos * 16) = o1;
    *(uint4*)(eaS + (size_t)pos * 16 + 8) = o2;
  }
}

// ---------------------------------------------------------------------------
// Kernel 1: node-side first-layer GEMMs via MFMA; A from bf16 hb/tb.
// ---------------------------------------------------------------------------
__global__ void __launch_bounds__(256) k_pre2(
    const unsigned short* __restrict__ hb, const unsigned short* __restrict__ tb,
    const float* __restrict__ We_w1, const float* __restrict__ We_b1,
    const float* __restrict__ Wx_w1, const float* __restrict__ Wx_b1,
    const float* __restrict__ Wh_w1, const float* __restrict__ Wh_b1,
    unsigned short* __restrict__ Aes, unsigned short* __restrict__ Aed,
    unsigned short* __restrict__ Axs, unsigned short* __restrict__ Axd,
    unsigned short* __restrict__ zpre, int N)
{
  __shared__ unsigned short Wt[128 * 168];
  __shared__ unsigned short OutS[64 * 136];

  const int group = blockIdx.y;
  const float* Wsrc = (group <= 1) ? We_w1 : (group <= 3) ? Wx_w1 : Wh_w1;
  const float* bias = (group == 0) ? We_b1 : (group == 2) ? Wx_b1
                    : (group == 4) ? Wh_b1 : nullptr;
  unsigned short* out = (group == 0) ? Aes : (group == 1) ? Aed
                      : (group == 2) ? Axs : (group == 3) ? Axd : zpre;
  const int rowBase = (group == 1 || group == 3) ? 128 : 0;
  const int tBase   = (group == 0) ? 273 : (group == 2) ? 272 : -1;

  for (int i = threadIdx.x; i < 160 * 128; i += 256){
    int k = i >> 7, col = i & 127;
    float wv = 0.f;
    if (k < 128)      wv = Wsrc[(rowBase + k) * 128 + col];
    else if (tBase >= 0) wv = Wsrc[(tBase + (k - 128)) * 128 + col];
    Wt[col * 168 + k] = f2b(wv);
  }
  __syncthreads();

  const int lane = threadIdx.x & 63, w = threadIdx.x >> 6;
  const int m = lane & 15, q = lane >> 4;
  float bb[8];
  #pragma unroll
  for (int t = 0; t < 8; ++t) bb[t] = bias ? bias[t * 16 + m] : 0.f;

  const int ntiles = (N + 63) >> 6;
  for (int tile = blockIdx.x; tile < ntiles; tile += gridDim.x){
    const int n0 = tile << 6;
    const int n = min(n0 + w * 16 + m, N - 1);

    short8 a[5];
    #pragma unroll
    for (int step = 0; step < 4; ++step)
      a[step] = *(const short8*)(hb + (size_t)n * 128 + step * 32 + q * 8);
    a[4] = *(const short8*)(tb + (size_t)n * 32 + q * 8);

    float4v acc[8];
    #pragma unroll
    for (int t = 0; t < 8; ++t) acc[t] = (float4v){0.f, 0.f, 0.f, 0.f};
    #pragma unroll
    for (int step = 0; step < 5; ++step){
      #pragma unroll
      for (int t = 0; t < 8; ++t){
        short8 b = *(const short8*)(Wt + (size_t)(t * 16 + m) * 168 + step * 32 + q * 8);
        acc[t] = __builtin_amdgcn_mfma_f32_16x16x32_bf16(a[step], b, acc[t], 0, 0, 0);
      }
    }

    #pragma unroll
    for (int t = 0; t < 8; ++t)
      #pragma unroll
      for (int r = 0; r < 4; ++r)
        OutS[(w * 16 + q * 4 + r) * 136 + t * 16 + m] = f2b(acc[t][r] + bb[t]);
    __syncthreads();
    for (int i = threadIdx.x; i < 64 * 16; i += 256){
      int node = i >> 4, seg = i & 15;
      int nn = n0 + node;
      if (nn < N)
        *(uint4*)(out + (size_t)nn * 128 + seg * 8) =
            *(const uint4*)(OutS + node * 136 + seg * 8);
    }
    __syncthreads();
  }
}

// ---------------------------------------------------------------------------
// Kernel 2: message path over dst-SORTED edges. v5:
//  - LDS diet: only S (stride 140, bank-fix) + 1KB tables -> 4 blocks/CU,
//    8 waves/SIMD (occupancy 2x) to hide gather latency.
//  - W2T/Btl fragments from GLOBAL (L1/L2-broadcast-resident tables).
//  - per-edge scalars precomputed in k_scatter (daux, eaS); cross-lane
//    scalar distribution via __shfl, not LDS.
// ---------------------------------------------------------------------------
__global__ void __launch_bounds__(512, 8) k_edge_msg(
    const int* __restrict__ ss, const int* __restrict__ ddv,
    const unsigned short* __restrict__ eaS, const float4* __restrict__ daux,
    const unsigned short* __restrict__ Aes, const unsigned short* __restrict__ Aed,
    const unsigned short* __restrict__ W2Te, const unsigned short* __restrict__ BtlE,
    const float* __restrict__ We_b2, const float* __restrict__ Watt_w,
    const float* __restrict__ Watt_b,
    unsigned short* __restrict__ msg_agg, int E)
{
  __shared__ __align__(16) unsigned short Ssh[8][16 * 140];  // 35840 B
  __shared__ __align__(16) float b2l[128];                   // 512 B
  __shared__ __align__(16) float wal[128];                   // 512 B
  // total 36864 B -> 4 blocks/CU (32 waves)

  const int tid = threadIdx.x;
  for (int i = tid; i < 128; i += 512){ b2l[i] = We_b2[i]; wal[i] = Watt_w[i]; }
  __syncthreads();

  const int lane = tid & 63, w = tid >> 6;
  const int m = lane & 15, q = lane >> 4;
  const float attb = Watt_b[0];
  unsigned short* S = Ssh[w];

  const int tiles = (E + 15) >> 4;
  const int wid = blockIdx.x * 8 + w;
  const int nwv = gridDim.x * 8;

  for (int tb = wid; tb < tiles; tb += nwv){
    const int e0 = tb << 4;

    // per-edge scalars (lanes 0..15), distributed via shfl
    int smy = 0, dmy = 0; float dval = 0.f;
    if (lane < 16){
      const int eC = min(e0 + lane, E - 1);
      smy = ss[eC]; dmy = ddv[eC]; dval = daux[eC].w;
    }
    const float dm = __shfl(dval, m);   // dist of edge m (all lanes)

    // staging: sums Aes[s]+Aed[d] -> S[edge][n] bf16
    #pragma unroll
    for (int it = 0; it < 4; ++it){
      const int eg = q + 4 * it;
      const int s = __shfl(smy, eg), d = __shfl(dmy, eg);
      uint4 gs = *(const uint4*)(Aes + (size_t)s * HD + m * 8);
      uint4 gd = *(const uint4*)(Aed + (size_t)d * HD + m * 8);
      float fa[8], fb[8];
      unp8(gs, fa); unp8(gd, fb);
      union { short8 v; unsigned int u[4]; } sv;
      #pragma unroll
      for (int jj = 0; jj < 4; ++jj)
        sv.u[jj] = packtrunc(fa[2 * jj] + fb[2 * jj], fa[2 * jj + 1] + fb[2 * jj + 1]);
      *(short8*)(S + eg * 140 + m * 8) = sv.v;
    }

    // tail B-frag (input^T): lane = edge m, k-slice q*8; k<16=ea, k==16=dist
    union { short8 v; unsigned int u[4]; } at;
    at.u[0] = at.u[1] = at.u[2] = at.u[3] = 0u;
    if (q < 2){
      at.v = *(const short8*)(eaS + (size_t)min(e0 + m, E - 1) * 16 + q * 8);
    } else if (q == 2){
      at.u[0] = __float_as_uint(dm) >> 16;
    }

    // tail MFMA swapped (A = W1tail^T from global), C init from staged sums
    #pragma unroll
    for (int t = 0; t < 8; ++t){
      uint2 cv = *(const uint2*)(S + m * 140 + t * 16 + q * 4);
      float4v ci;
      ci[0] = unplo(cv.x); ci[1] = unphi(cv.x);
      ci[2] = unplo(cv.y); ci[3] = unphi(cv.y);
      short8 aB;
      if (q < 3) aB = *(const short8*)(BtlE + (t * 16 + m) * 24 + q * 8);
      else { union { short8 v; unsigned int u[4]; } z; z.u[0]=z.u[1]=z.u[2]=z.u[3]=0u; aB = z.v; }
      float4v o = __builtin_amdgcn_mfma_f32_16x16x32_bf16(aB, at.v, ci, 0, 0, 0);
      uint2 ov;
      ov.x = packtrunc(siluf(o[0]), siluf(o[1]));
      ov.y = packtrunc(siluf(o[2]), siluf(o[3]));
      *(uint2*)(S + m * 140 + t * 16 + q * 4) = ov;
    }

    // layer-2 MFMA swapped: A = W2^T frags from GLOBAL, B = u^T from S
    float4v c2[8];
    #pragma unroll
    for (int t = 0; t < 8; ++t) c2[t] = (float4v){0.f, 0.f, 0.f, 0.f};
    #pragma unroll
    for (int step = 0; step < 4; ++step){
      short8 bU = *(const short8*)(S + m * 140 + step * 32 + q * 8);
      #pragma unroll
      for (int t = 0; t < 8; ++t){
        short8 aW = *(const short8*)(W2Te + (size_t)(t * 16 + m) * 128 + step * 32 + q * 8);
        c2[t] = __builtin_amdgcn_mfma_f32_16x16x32_bf16(aW, bU, c2[t], 0, 0, 0);
      }
    }

    // attention: lane holds edge m's n-values {t*16+q*4+r}; 1 sigmoid/lane
    float p = 0.f;
    #pragma unroll
    for (int t = 0; t < 8; ++t){
      float4 bv = *(const float4*)(b2l + t * 16 + q * 4);
      float4 wv = *(const float4*)(wal + t * 16 + q * 4);
      c2[t][0] += bv.x; c2[t][1] += bv.y; c2[t][2] += bv.z; c2[t][3] += bv.w;
      p = fmaf(c2[t][0], wv.x, p); p = fmaf(c2[t][1], wv.y, p);
      p = fmaf(c2[t][2], wv.z, p); p = fmaf(c2[t][3], wv.w, p);
    }
    p += __shfl_xor(p, 16); p += __shfl_xor(p, 32);
    const float att = rcpf(1.f + __expf(-(p + attb)));
    #pragma unroll
    for (int t = 0; t < 8; ++t){
      uint2 ov;
      ov.x = packtrunc(att * c2[t][0], att * c2[t][1]);
      ov.y = packtrunc(att * c2[t][2], att * c2[t][3]);
      *(uint2*)(S + m * 140 + t * 16 + q * 4) = ov;
    }

    // segmented f32 reduction over sorted dsts (2 halves of 8 for reg budget)
    float a0 = 0.f, a1 = 0.f;
    int dp = __shfl(dmy, 0);
    #pragma unroll
    for (int half = 0; half < 2; ++half){
      unsigned int vv[8]; int dvr[8];
      #pragma unroll
      for (int j = 0; j < 8; ++j){
        const int eg = half * 8 + j;
        vv[j]  = *(const unsigned int*)(S + eg * 140 + lane * 2);
        dvr[j] = __shfl(dmy, eg);
      }
      #pragma unroll
      for (int j = 0; j < 8; ++j){
        if (dvr[j] != dp){                      // wave-uniform branch
          atomAddBF2(msg_agg + (size_t)dp * HD + lane * 2, packbf(a0, a1));
          a0 = a1 = 0.f; dp = dvr[j];
        }
        if (e0 + half * 8 + j < E){ a0 += unplo(vv[j]); a1 += unphi(vv[j]); }
      }
    }
    atomAddBF2(msg_agg + (size_t)dp * HD + lane * 2, packbf(a0, a1));
  }
}

// ---------------------------------------------------------------------------
// Kernel 3: coord path over dst-SORTED edges. Same v5 treatment; the
// per-edge contribution distribution uses shfl only (no LDS xc buffer).
// ---------------------------------------------------------------------------
__global__ void __launch_bounds__(512, 8) k_edge_coord(
    const int* __restrict__ ss, const int* __restrict__ ddv,
    const unsigned short* __restrict__ eaS, const float4* __restrict__ daux,
    const unsigned short* __restrict__ Axs, const unsigned short* __restrict__ Axd,
    const unsigned short* __restrict__ W2Tx, const unsigned short* __restrict__ BtlX,
    const float* __restrict__ Wx_b2, const float* __restrict__ Wx_w3,
    float* __restrict__ xout, int E)
{
  __shared__ __align__(16) unsigned short Ssh[8][16 * 140];  // 35840 B
  __shared__ __align__(16) float b2l[128];
  __shared__ __align__(16) float w3l[128];
  // total 36864 B -> 4 blocks/CU

  const int tid = threadIdx.x;
  for (int i = tid; i < 128; i += 512){ b2l[i] = Wx_b2[i]; w3l[i] = Wx_w3[i]; }
  __syncthreads();

  const int lane = tid & 63, w = tid >> 6;
  const int m = lane & 15, q = lane >> 4;
  unsigned short* S = Ssh[w];

  const int tiles = (E + 15) >> 4;
  const int wid = blockIdx.x * 8 + w;
  const int nwv = gridDim.x * 8;

  for (int tb = wid; tb < tiles; tb += nwv){
    const int e0 = tb << 4;

    int smy = 0, dmy = 0;
    float dxv = 0.f, dyv = 0.f, dzv = 0.f, rsv = 0.f;
    if (lane < 16){
      const int eC = min(e0 + lane, E - 1);
      smy = ss[eC]; dmy = ddv[eC];
      float4 d4 = daux[eC];
      dxv = d4.x; dyv = d4.y; dzv = d4.z;
      rsv = 2.5f / (sqrtf(d4.w + 1e-8f) + 1.0f);
    }
    const float dxm = __shfl(dxv, m), dym = __shfl(dyv, m);
    const float dzm = __shfl(dzv, m), rsm = __shfl(rsv, m);

    #pragma unroll
    for (int it = 0; it < 4; ++it){
      const int eg = q + 4 * it;
      const int s = __shfl(smy, eg), d = __shfl(dmy, eg);
      uint4 gs = *(const uint4*)(Axs + (size_t)s * HD + m * 8);
      uint4 gd = *(const uint4*)(Axd + (size_t)d * HD + m * 8);
      float fa[8], fb[8];
      unp8(gs, fa); unp8(gd, fb);
      union { short8 v; unsigned int u[4]; } sv;
      #pragma unroll
      for (int jj = 0; jj < 4; ++jj)
        sv.u[jj] = packtrunc(fa[2 * jj] + fb[2 * jj], fa[2 * jj + 1] + fb[2 * jj + 1]);
      *(short8*)(S + eg * 140 + m * 8) = sv.v;
    }

    // tail B-frag (ea only, k<16)
    union { short8 v; unsigned int u[4]; } at;
    at.u[0] = at.u[1] = at.u[2] = at.u[3] = 0u;
    if (q < 2)
      at.v = *(const short8*)(eaS + (size_t)min(e0 + m, E - 1) * 16 + q * 8);

    #pragma unroll
    for (int t = 0; t < 8; ++t){
      uint2 cv = *(const uint2*)(S + m * 140 + t * 16 + q * 4);
      float4v ci;
      ci[0] = unplo(cv.x); ci[1] = unphi(cv.x);
      ci[2] = unplo(cv.y); ci[3] = unphi(cv.y);
      short8 aB;
      if (q < 2) aB = *(const short8*)(BtlX + (t * 16 + m) * 16 + q * 8);
      else { union { short8 v; unsigned int u[4]; } z; z.u[0]=z.u[1]=z.u[2]=z.u[3]=0u; aB = z.v; }
      float4v o = __builtin_amdgcn_mfma_f32_16x16x32_bf16(aB, at.v, ci, 0, 0, 0);
      uint2 ov;
      ov.x = packtrunc(siluf(o[0]), siluf(o[1]));
      ov.y = packtrunc(siluf(o[2]), siluf(o[3]));
      *(uint2*)(S + m * 140 + t * 16 + q * 4) = ov;
    }

    float4v c2[8];
    #pragma unroll
    for (int t = 0; t < 8; ++t) c2[t] = (float4v){0.f, 0.f, 0.f, 0.f};
    #pragma unroll
    for (int step = 0; step < 4; ++step){
      short8 bU = *(const short8*)(S + m * 140 + step * 32 + q * 8);
      #pragma unroll
      for (int t = 0; t < 8; ++t){
        short8 aW = *(const short8*)(W2Tx + (size_t)(t * 16 + m) * 128 + step * 32 + q * 8);
        c2[t] = __builtin_amdgcn_mfma_f32_16x16x32_bf16(aW, bU, c2[t], 0, 0, 0);
      }
    }

    // coord weight: lane holds edge m; 1 tanh/lane via exp+rcp
    float p = 0.f;
    #pragma unroll
    for (int t = 0; t < 8; ++t){
      float4 bv = *(const float4*)(b2l + t * 16 + q * 4);
      float4 wv = *(const float4*)(w3l + t * 16 + q * 4);
      p = fmaf(siluf(c2[t][0] + bv.x), wv.x, p);
      p = fmaf(siluf(c2[t][1] + bv.y), wv.y, p);
      p = fmaf(siluf(c2[t][2] + bv.z), wv.z, p);
      p = fmaf(siluf(c2[t][3] + bv.w), wv.w, p);
    }
    p += __shfl_xor(p, 16); p += __shfl_xor(p, 32);
    const float th = 1.f - 2.f * rcpf(1.f + __expf(2.f * p));  // tanh(p)
    const float sc = th * rsm;
    const float comp = (q == 0) ? dxm : (q == 1) ? dym : dzm;
    const float contrib = comp * sc;   // meaningful for q<3

    // segmented emit: lanes 0..2 emit; contributions pulled via shfl
    int dp = __shfl(dmy, 0); float acc = 0.f;
    #pragma unroll
    for (int eg = 0; eg < 16; ++eg){
      int dc = __shfl(dmy, eg);
      float c = __shfl(contrib, ((lane & 3) << 4) + eg);
      if (dc != dp){                               // wave-uniform
        if (lane < 3) atomAddF(xout + (size_t)dp * 3 + lane, acc);
        acc = 0.f; dp = dc;
      }
      if (e0 + eg < E) acc += c;
    }
    if (lane < 3) atomAddF(xout + (size_t)dp * 3 + lane, acc);
  }
}

// ---------------------------------------------------------------------------
// Kernel 4: z2 = bf16( silu( zpre + msg @ Wh_w1[128:256] ) ) — msg bf16.
// ---------------------------------------------------------------------------
__global__ void __launch_bounds__(256) k_h1b2(
    const unsigned short* __restrict__ msg, const unsigned short* __restrict__ zpre,
    const float* __restrict__ Wh_w1, unsigned short* __restrict__ z2, int N)
{
  __shared__ unsigned short Wt[128 * 136];
  __shared__ unsigned short OutS[64 * 136];

  for (int i = threadIdx.x; i < 128 * 128; i += 256){
    int k = i >> 7, col = i & 127;
    Wt[col * 136 + k] = f2b(Wh_w1[(128 + k) * 128 + col]);
  }
  __syncthreads();

  const int lane = threadIdx.x & 63, w = threadIdx.x >> 6;
  const int m = lane & 15, q = lane >> 4;

  const int ntiles = (N + 63) >> 6;
  for (int tile = blockIdx.x; tile < ntiles; tile += gridDim.x){
    const int n0 = tile << 6;
    const int n = min(n0 + w * 16 + m, N - 1);

    short8 a[4];
    #pragma unroll
    for (int step = 0; step < 4; ++step)
      a[step] = *(const short8*)(msg + (size_t)n * 128 + step * 32 + q * 8);

    float4v acc[8];
    #pragma unroll
    for (int t = 0; t < 8; ++t) acc[t] = (float4v){0.f, 0.f, 0.f, 0.f};
    #pragma unroll
    for (int step = 0; step < 4; ++step){
      #pragma unroll
      for (int t = 0; t < 8; ++t){
        short8 b = *(const short8*)(Wt + (size_t)(t * 16 + m) * 136 + step * 32 + q * 8);
        acc[t] = __builtin_amdgcn_mfma_f32_16x16x32_bf16(a[step], b, acc[t], 0, 0, 0);
      }
    }

    #pragma unroll
    for (int t = 0; t < 8; ++t)
      #pragma unroll
      for (int r = 0; r < 4; ++r)
        OutS[(w * 16 + q * 4 + r) * 136 + t * 16 + m] = f2b(acc[t][r]);
    __syncthreads();
    for (int i = threadIdx.x; i < 64 * 16; i += 256){
      int node = i >> 4, seg = i & 15;
      int nn = n0 + node;
      if (nn < N){
        uint4 dv = *(const uint4*)(OutS + node * 136 + seg * 8);
        uint4 zv = *(const uint4*)(zpre + (size_t)nn * 128 + seg * 8);
        float fd[8], fz[8];
        unp8(dv, fd); unp8(zv, fz);
        uint4 ov;
        ov.x = packbf(siluf(fz[0] + fd[0]), siluf(fz[1] + fd[1]));
        ov.y = packbf(siluf(fz[2] + fd[2]), siluf(fz[3] + fd[3]));
        ov.z = packbf(siluf(fz[4] + fd[4]), siluf(fz[5] + fd[5]));
        ov.w = packbf(siluf(fz[6] + fd[6]), siluf(fz[7] + fd[7]));
        *(uint4*)(z2 + (size_t)nn * 128 + seg * 8) = ov;
      }
    }
    __syncthreads();
  }
}

// ---------------------------------------------------------------------------
// Kernel 5: hout = h + z2 @ Wh_w2 + Wh_b2
// ---------------------------------------------------------------------------
__global__ void __launch_bounds__(256) k_h22(
    const float* __restrict__ h, const unsigned short* __restrict__ z2,
    const float* __restrict__ Wh_w2, const float* __restrict__ Wh_b2,
    float* __restrict__ hout, int N)
{
  __shared__ unsigned short Wt[128 * 136];
  __shared__ float OutSf[64 * 132];

  for (int i = threadIdx.x; i < 128 * 128; i += 256){
    int k = i >> 7, col = i & 127;
    Wt[col * 136 + k] = f2b(Wh_w2[k * 128 + col]);
  }
  __syncthreads();

  const int lane = threadIdx.x & 63, w = threadIdx.x >> 6;
  const int m = lane & 15, q = lane >> 4;
  float bb[8];
  #pragma unroll
  for (int t = 0; t < 8; ++t) bb[t] = Wh_b2[t * 16 + m];

  const int ntiles = (N + 63) >> 6;
  for (int tile = blockIdx.x; tile < ntiles; tile += gridDim.x){
    const int n0 = tile << 6;
    const int n = min(n0 + w * 16 + m, N - 1);

    short8 a[4];
    #pragma unroll
    for (int step = 0; step < 4; ++step)
      a[step] = *(const short8*)(z2 + (size_t)n * 128 + step * 32 + q * 8);

    float4v acc[8];
    #pragma unroll
    for (int t = 0; t < 8; ++t) acc[t] = (float4v){0.f, 0.f, 0.f, 0.f};
    #pragma unroll
    for (int step = 0; step < 4; ++step){
      #pragma unroll
      for (int t = 0; t < 8; ++t){
        short8 b = *(const short8*)(Wt + (size_t)(t * 16 + m) * 136 + step * 32 + q * 8);
        acc[t] = __builtin_amdgcn_mfma_f32_16x16x32_bf16(a[step], b, acc[t], 0, 0, 0);
      }
    }

    #pragma unroll
    for (int t = 0; t < 8; ++t)
      #pragma unroll
      for (int r = 0; r < 4; ++r)
        OutSf[(w * 16 + q * 4 + r) * 132 + t * 16 + m] = acc[t][r] + bb[t];
    __syncthreads();
    for (int i = threadIdx.x; i < 64 * 32; i += 256){
      int node = i >> 5, seg = i & 31;
      int nn = n0 + node;
      if (nn < N){
        float4 dv = *(const float4*)(OutSf + node * 132 + seg * 4);
        float4 hv = *(const float4*)(h + (size_t)nn * 128 + seg * 4);
        float4 ov = {hv.x + dv.x, hv.y + dv.y, hv.z + dv.z, hv.w + dv.w};
        *(float4*)(hout + (size_t)nn * 128 + seg * 4) = ov;
      }
    }
    __syncthreads();
  }
}

extern "C" void kernel_launch(void* const* d_in, const int* in_sizes, int n_in,
                              void* d_out, int out_size, void* d_ws, size_t ws_size,
                              hipStream_t stream)
{
  const float* h      = (const float*)d_in[0];
  const float* x      = (const float*)d_in[1];
  const int*   ei     = (const int*)  d_in[2];
  const float* ea     = (const float*)d_in[3];
  const float* t_emb  = (const float*)d_in[4];
  const float* We_w1  = (const float*)d_in[5];
  const float* We_b1  = (const float*)d_in[6];
  const float* We_w2  = (const float*)d_in[7];
  const float* We_b2  = (const float*)d_in[8];
  const float* Watt_w = (const float*)d_in[9];
  const float* Watt_b = (const float*)d_in[10];
  const float* Wx_w1  = (const float*)d_in[11];
  const float* Wx_b1  = (const float*)d_in[12];
  const float* Wx_w2  = (const float*)d_in[13];
  const float* Wx_b2  = (const float*)d_in[14];
  const float* Wx_w3  = (const float*)d_in[15];
  const float* Wh_w1  = (const float*)d_in[16];
  const float* Wh_b1  = (const float*)d_in[17];
  const float* Wh_w2  = (const float*)d_in[18];
  const float* Wh_b2  = (const float*)d_in[19];

  const int N = in_sizes[0] / HD;
  const int E = in_sizes[2] / 2;

  char* ws = (char*)d_ws;
  unsigned short* Aes  = (unsigned short*)ws;  ws += (size_t)N * HD * 2;
  unsigned short* Aed  = (unsigned short*)ws;  ws += (size_t)N * HD * 2;
  unsigned short* Axs  = (unsigned short*)ws;  ws += (size_t)N * HD * 2;
  unsigned short* Axd  = (unsigned short*)ws;  ws += (size_t)N * HD * 2;
  unsigned short* zpre = (unsigned short*)ws;  ws += (size_t)N * HD * 2;
  unsigned short* z2   = (unsigned short*)ws;  ws += (size_t)N * HD * 2;
  unsigned short* msg_agg = (unsigned short*)ws; ws += (size_t)N * HD * 2;
  unsigned short* hb   = (unsigned short*)ws;  ws += (size_t)N * HD * 2;
  unsigned short* tb   = (unsigned short*)ws;  ws += (size_t)N * TD * 2;

  // Overlays into [hb, hb+16MB) AFTER k_pre2 consumed hb/tb:
  //   ss (E ints) | ddv (E ints) | daux (E float4) | weight tables (~76KB)
  char* sortbase = (char*)hb;
  int*    ss_   = (int*)sortbase;
  int*    ddv_  = ss_ + E;
  float4* daux_ = (float4*)(sortbase + (size_t)8 * E);
  unsigned short* W2Te_ = (unsigned short*)(sortbase + (size_t)24 * E);
  unsigned short* W2Tx_ = W2Te_ + 128 * 128;
  unsigned short* BtlE_ = W2Tx_ + 128 * 128;
  unsigned short* BtlX_ = BtlE_ + 128 * 24;
  // cnt/off live in msg_agg's first 2N ints during sort (re-zeroed after)
  int* cnt_ = (int*)msg_agg;
  int* off_ = cnt_ + N;

  float* hout = (float*)d_out;
  float* xout = hout + (size_t)N * HD;
  // eaS (E x 16 bf16, sorted order) borrows hout space; k_h22 (last kernel)
  // fully overwrites hout afterwards. Stream order guarantees safety.
  unsigned short* eaS_ = (unsigned short*)hout;

  hipMemsetAsync(msg_agg, 0, (size_t)N * HD * 2, stream);   // also zeroes cnt/off
  hipMemcpyAsync(xout, x, (size_t)N * 3 * 4, hipMemcpyDeviceToDevice, stream);

  k_cvt<<<400, 256, 0, stream>>>(h, hb, N * (HD / 8));
  k_cvt<<<100, 256, 0, stream>>>(t_emb, tb, N * (TD / 8));

  dim3 gP(192, 5);
  k_pre2<<<gP, 256, 0, stream>>>(hb, tb, We_w1, We_b1, Wx_w1, Wx_b1,
                                 Wh_w1, Wh_b1, Aes, Aed, Axs, Axd, zpre, N);

  k_prepw<<<64, 256, 0, stream>>>(We_w2, Wx_w2, We_w1, Wx_w1,
                                  W2Te_, W2Tx_, BtlE_, BtlX_);

  // counting sort by dst + per-edge precompute
  k_hist<<<512, 256, 0, stream>>>(ei, cnt_, E);
  k_scan<<<1, 1024, 0, stream>>>(cnt_, off_, N);
  k_scatter<<<1024, 256, 0, stream>>>(ei, x, ea, off_, ss_, ddv_, daux_, eaS_, E);

  // re-zero the msg_agg area that hosted cnt/off
  hipMemsetAsync(msg_agg, 0, (size_t)2 * N * sizeof(int), stream);

  k_edge_msg<<<1024, 512, 0, stream>>>(ss_, ddv_, eaS_, daux_, Aes, Aed,
                                       W2Te_, BtlE_, We_b2, Watt_w, Watt_b,
                                       msg_agg, E);
  k_edge_coord<<<1024, 512, 0, stream>>>(ss_, ddv_, eaS_, daux_, Axs, Axd,
                                         W2Tx_, BtlX_, Wx_b2, Wx_w3, xout, E);
  k_h1b2<<<512, 256, 0, stream>>>(msg_agg, zpre, Wh_w1, z2, N);
  k_h22<<<512, 256, 0, stream>>>(h, z2, Wh_w2, Wh_b2, hout, N);
}

// Round 6
// 577.477 us; speedup vs baseline: 2.5632x; 2.5632x over previous
//
#include <hip/hip_runtime.h>
#include <hip/hip_bf16.h>

#define HD 128
#define ED 16
#define TD 32

typedef __attribute__((ext_vector_type(8))) short short8;
typedef __attribute__((ext_vector_type(4))) float float4v;

__device__ __forceinline__ float rcpf(float x){ return __builtin_amdgcn_rcpf(x); }
__device__ __forceinline__ float siluf(float v){ return v * rcpf(1.0f + __expf(-v)); }

// bf16 pack/unpack helpers
__device__ __forceinline__ unsigned int bfbits(float x){          // RTNE
  unsigned int a = __float_as_uint(x);
  return (a + 0x7fffu + ((a >> 16) & 1u)) >> 16;
}
__device__ __forceinline__ unsigned int packbf(float lo, float hi){  // RTNE pair
  return (bfbits(lo) & 0xffffu) | (bfbits(hi) << 16);
}
// 1-op truncation pack via v_perm_b32: [lo.b2, lo.b3, hi.b2, hi.b3]
__device__ __forceinline__ unsigned int packtrunc(float lo, float hi){
  return __builtin_amdgcn_perm(__float_as_uint(hi), __float_as_uint(lo), 0x07060302u);
}
__device__ __forceinline__ float unplo(unsigned int w){ return __uint_as_float(w << 16); }
__device__ __forceinline__ float unphi(unsigned int w){ return __uint_as_float(w & 0xffff0000u); }
__device__ __forceinline__ unsigned short f2b(float x){ return (unsigned short)bfbits(x); }

__device__ __forceinline__ void unp8(uint4 u, float* f){
  f[0]=unplo(u.x); f[1]=unphi(u.x); f[2]=unplo(u.y); f[3]=unphi(u.y);
  f[4]=unplo(u.z); f[5]=unphi(u.z); f[6]=unplo(u.w); f[7]=unphi(u.w);
}

__device__ __forceinline__ void atomAddF(float* p, float v){
  unsafeAtomicAdd(p, v);  // HW global_atomic_add_f32 on gfx950
}

// packed bf16 atomic add: one instruction adds 2 bf16 lanes-worth
__device__ __forceinline__ void atomAddBF2(unsigned short* p, unsigned int packed){
  asm volatile("global_atomic_pk_add_bf16 %0, %1, off"
               :: "v"((unsigned long long)(uintptr_t)p), "v"(packed) : "memory");
}

// ---------------------------------------------------------------------------
// Kernel 0: fp32 -> bf16 (RTNE) stream convert, 8 elems/thread-iter.
// ---------------------------------------------------------------------------
__global__ void __launch_bounds__(256) k_cvt(
    const float* __restrict__ src, unsigned short* __restrict__ dst, int n8)
{
  for (int i = blockIdx.x * 256 + threadIdx.x; i < n8; i += gridDim.x * 256){
    float4 v0 = *(const float4*)(src + (size_t)i * 8);
    float4 v1 = *(const float4*)(src + (size_t)i * 8 + 4);
    uint4 o;
    o.x = packbf(v0.x, v0.y); o.y = packbf(v0.z, v0.w);
    o.z = packbf(v1.x, v1.y); o.w = packbf(v1.z, v1.w);
    *(uint4*)(dst + (size_t)i * 8) = o;
  }
}

// ---------------------------------------------------------------------------
// Sort-by-dst preprocessing: hist -> scan -> scatter.
// k_scatter hoists per-edge scalar work: daux = (dx,dy,dz,dist),
// eaS = edge_attr in sorted order as bf16.
// ---------------------------------------------------------------------------
__global__ void __launch_bounds__(256) k_hist(
    const int* __restrict__ ei, int* __restrict__ cnt, int E)
{
  for (int e = blockIdx.x * 256 + threadIdx.x; e < E; e += gridDim.x * 256)
    atomicAdd(&cnt[ei[E + e]], 1);
}

__global__ void __launch_bounds__(1024) k_scan(
    const int* __restrict__ cnt, int* __restrict__ off, int n)
{
  const int tid = threadIdx.x, lane = tid & 63, wv = tid >> 6;  // 16 waves
  __shared__ int wsum[16];
  __shared__ int carryS;
  if (tid == 0) carryS = 0;
  __syncthreads();
  const int CH = 1024 * 8;
  for (int base = 0; base < n; base += CH){
    const int idx0 = base + tid * 8;
    int v[8];
    #pragma unroll
    for (int j = 0; j < 8; ++j){ int i = idx0 + j; v[j] = (i < n) ? cnt[i] : 0; }
    #pragma unroll
    for (int j = 1; j < 8; ++j) v[j] += v[j - 1];   // local inclusive
    const int tot = v[7];
    int sc = tot;                                    // wave inclusive scan
    #pragma unroll
    for (int d = 1; d < 64; d <<= 1){ int t = __shfl_up(sc, d); if (lane >= d) sc += t; }
    if (lane == 63) wsum[wv] = sc;
    __syncthreads();
    if (tid < 16){
      int s = wsum[tid];
      #pragma unroll
      for (int d = 1; d < 16; d <<= 1){ int t = __shfl_up(s, d); if (tid >= d) s += t; }
      wsum[tid] = s;
    }
    __syncthreads();
    const int base_excl = carryS + (wv > 0 ? wsum[wv - 1] : 0) + (sc - tot);
    #pragma unroll
    for (int j = 0; j < 8; ++j){
      int i = idx0 + j;
      if (i < n) off[i] = base_excl + (j > 0 ? v[j - 1] : 0);
    }
    __syncthreads();
    if (tid == 0) carryS += wsum[15];
    __syncthreads();
  }
}

__global__ void __launch_bounds__(256) k_scatter(
    const int* __restrict__ ei, const float* __restrict__ x,
    const float* __restrict__ ea, int* __restrict__ off,
    int* __restrict__ ss, int* __restrict__ ddv,
    float4* __restrict__ daux, unsigned short* __restrict__ eaS, int E)
{
  for (int e = blockIdx.x * 256 + threadIdx.x; e < E; e += gridDim.x * 256){
    int s = ei[e], d = ei[E + e];
    int pos = atomicAdd(&off[d], 1);
    ss[pos] = s; ddv[pos] = d;
    float dx = x[s * 3 + 0] - x[d * 3 + 0];
    float dy = x[s * 3 + 1] - x[d * 3 + 1];
    float dz = x[s * 3 + 2] - x[d * 3 + 2];
    float4 da; da.x = dx; da.y = dy; da.z = dz; da.w = dx*dx + dy*dy + dz*dz;
    daux[pos] = da;
    const float4* e4 = (const float4*)(ea + (size_t)e * ED);
    float4 a = e4[0], b = e4[1], c = e4[2], dd = e4[3];
    uint4 o1, o2;
    o1.x = packtrunc(a.x, a.y); o1.y = packtrunc(a.z, a.w);
    o1.z = packtrunc(b.x, b.y); o1.w = packtrunc(b.z, b.w);
    o2.x = packtrunc(c.x, c.y); o2.y = packtrunc(c.z, c.w);
    o2.z = packtrunc(dd.x, dd.y); o2.w = packtrunc(dd.z, dd.w);
    *(uint4*)(eaS + (size_t)pos * 16) = o1;
    *(uint4*)(eaS + (size_t)pos * 16 + 8) = o2;
  }
}

// ---------------------------------------------------------------------------
// Kernel 1: node-side first-layer GEMMs via MFMA; A from bf16 hb/tb.
// ---------------------------------------------------------------------------
__global__ void __launch_bounds__(256) k_pre2(
    const unsigned short* __restrict__ hb, const unsigned short* __restrict__ tb,
    const float* __restrict__ We_w1, const float* __restrict__ We_b1,
    const float* __restrict__ Wx_w1, const float* __restrict__ Wx_b1,
    const float* __restrict__ Wh_w1, const float* __restrict__ Wh_b1,
    unsigned short* __restrict__ Aes, unsigned short* __restrict__ Aed,
    unsigned short* __restrict__ Axs, unsigned short* __restrict__ Axd,
    unsigned short* __restrict__ zpre, int N)
{
  __shared__ unsigned short Wt[128 * 168];
  __shared__ unsigned short OutS[64 * 136];

  const int group = blockIdx.y;
  const float* Wsrc = (group <= 1) ? We_w1 : (group <= 3) ? Wx_w1 : Wh_w1;
  const float* bias = (group == 0) ? We_b1 : (group == 2) ? Wx_b1
                    : (group == 4) ? Wh_b1 : nullptr;
  unsigned short* out = (group == 0) ? Aes : (group == 1) ? Aed
                      : (group == 2) ? Axs : (group == 3) ? Axd : zpre;
  const int rowBase = (group == 1 || group == 3) ? 128 : 0;
  const int tBase   = (group == 0) ? 273 : (group == 2) ? 272 : -1;

  for (int i = threadIdx.x; i < 160 * 128; i += 256){
    int k = i >> 7, col = i & 127;
    float wv = 0.f;
    if (k < 128)      wv = Wsrc[(rowBase + k) * 128 + col];
    else if (tBase >= 0) wv = Wsrc[(tBase + (k - 128)) * 128 + col];
    Wt[col * 168 + k] = f2b(wv);
  }
  __syncthreads();

  const int lane = threadIdx.x & 63, w = threadIdx.x >> 6;
  const int m = lane & 15, q = lane >> 4;
  float bb[8];
  #pragma unroll
  for (int t = 0; t < 8; ++t) bb[t] = bias ? bias[t * 16 + m] : 0.f;

  const int ntiles = (N + 63) >> 6;
  for (int tile = blockIdx.x; tile < ntiles; tile += gridDim.x){
    const int n0 = tile << 6;
    const int n = min(n0 + w * 16 + m, N - 1);

    short8 a[5];
    #pragma unroll
    for (int step = 0; step < 4; ++step)
      a[step] = *(const short8*)(hb + (size_t)n * 128 + step * 32 + q * 8);
    a[4] = *(const short8*)(tb + (size_t)n * 32 + q * 8);

    float4v acc[8];
    #pragma unroll
    for (int t = 0; t < 8; ++t) acc[t] = (float4v){0.f, 0.f, 0.f, 0.f};
    #pragma unroll
    for (int step = 0; step < 5; ++step){
      #pragma unroll
      for (int t = 0; t < 8; ++t){
        short8 b = *(const short8*)(Wt + (size_t)(t * 16 + m) * 168 + step * 32 + q * 8);
        acc[t] = __builtin_amdgcn_mfma_f32_16x16x32_bf16(a[step], b, acc[t], 0, 0, 0);
      }
    }

    #pragma unroll
    for (int t = 0; t < 8; ++t)
      #pragma unroll
      for (int r = 0; r < 4; ++r)
        OutS[(w * 16 + q * 4 + r) * 136 + t * 16 + m] = f2b(acc[t][r] + bb[t]);
    __syncthreads();
    for (int i = threadIdx.x; i < 64 * 16; i += 256){
      int node = i >> 4, seg = i & 15;
      int nn = n0 + node;
      if (nn < N)
        *(uint4*)(out + (size_t)nn * 128 + seg * 8) =
            *(const uint4*)(OutS + node * 136 + seg * 8);
    }
    __syncthreads();
  }
}

// ---------------------------------------------------------------------------
// Kernel 2: message path over dst-SORTED edges. v6:
//  - r4 structure (W2t+Btl in LDS, swapped-operand MFMA, 2 blocks/CU),
//    NO register pipeline (r4's spill source).
//  - direct C-layout gathers: lane (edge m, q) loads Aes/Aed uint2 at
//    n = t*16+q*4 and f32-adds straight into the MFMA C operand — deletes
//    the staging LDS round-trip and its pack/unpack VALU entirely.
//  - 2-phase (4t + 4t) gather so only 16 regs in flight (no spill at 64 VGPR).
// ---------------------------------------------------------------------------
__global__ void __launch_bounds__(512, 4) k_edge_msg(
    const int* __restrict__ ss, const int* __restrict__ ddv,
    const unsigned short* __restrict__ eaS, const float4* __restrict__ daux,
    const unsigned short* __restrict__ Aes, const unsigned short* __restrict__ Aed,
    const float* __restrict__ We_w1, const float* __restrict__ We_w2,
    const float* __restrict__ We_b2, const float* __restrict__ Watt_w,
    const float* __restrict__ Watt_b,
    unsigned short* __restrict__ msg_agg, int E)
{
  __shared__ __align__(16) unsigned short W2t[128 * 136];   // 34816 B [col][k]
  __shared__ __align__(16) unsigned short Btl[128 * 24];    // 6144 B  [col][k<24]
  __shared__ __align__(16) unsigned short Ssh[8][16 * 140]; // 35840 B [edge][n]
  __shared__ __align__(16) float b2l[128];                  // 512 B
  __shared__ __align__(16) float wal[128];                  // 512 B
  // total 77824 B -> 2 blocks/CU (16 waves)

  const int tid = threadIdx.x;
  for (int i = tid; i < 128 * 128; i += 512){
    int col = i & 127, k = i >> 7;
    W2t[col * 136 + k] = f2b(We_w2[k * 128 + col]);
  }
  for (int i = tid; i < 128 * 24; i += 512){
    int col = i / 24, k = i % 24;
    float wv = (k < 16) ? We_w1[(257 + k) * 128 + col]
             : (k == 16 ? We_w1[256 * 128 + col] : 0.f);
    Btl[col * 24 + k] = f2b(wv);
  }
  for (int i = tid; i < 128; i += 512){ b2l[i] = We_b2[i]; wal[i] = Watt_w[i]; }
  __syncthreads();

  const int lane = tid & 63, w = tid >> 6;
  const int m = lane & 15, q = lane >> 4;
  const float attb = Watt_b[0];
  unsigned short* S = Ssh[w];

  const int tiles = (E + 15) >> 4;
  const int wid = blockIdx.x * 8 + w;
  const int nwv = gridDim.x * 8;

  for (int tb = wid; tb < tiles; tb += nwv){
    const int e0 = tb << 4;

    // per-edge indices/scalars (lanes 0..15), distributed via shfl
    int smy = 0, dmy = 0; float dval = 0.f;
    if (lane < 16){
      const int eC = min(e0 + lane, E - 1);
      smy = ss[eC]; dmy = ddv[eC]; dval = daux[eC].w;
    }
    const int s_m = __shfl(smy, m), d_m = __shfl(dmy, m);
    const float dm = __shfl(dval, m);

    // tail B-frag: lane = edge m, k-slice q*8; k<16 = ea, k==16 = dist
    union { short8 v; unsigned int u[4]; } at;
    at.u[0] = at.u[1] = at.u[2] = at.u[3] = 0u;
    if (q < 2){
      at.v = *(const short8*)(eaS + (size_t)min(e0 + m, E - 1) * 16 + q * 8);
    } else if (q == 2){
      at.u[0] = __float_as_uint(dm) >> 16;
    }

    // direct C-layout gather bases (lane owns edge m, n-offsets t*16+q*4)
    const unsigned short* pS = Aes + (size_t)s_m * HD + q * 4;
    const unsigned short* pD = Aed + (size_t)d_m * HD + q * 4;

    // tail MFMA swapped, 2 phases of 4 t's; C = f32 sum of gathers; silu->S
    #pragma unroll
    for (int ph = 0; ph < 2; ++ph){
      uint2 gs[4], gd[4];
      #pragma unroll
      for (int j = 0; j < 4; ++j){
        gs[j] = *(const uint2*)(pS + (ph * 4 + j) * 16);
        gd[j] = *(const uint2*)(pD + (ph * 4 + j) * 16);
      }
      #pragma unroll
      for (int j = 0; j < 4; ++j){
        const int t = ph * 4 + j;
        float4v ci;
        ci[0] = unplo(gs[j].x) + unplo(gd[j].x);
        ci[1] = unphi(gs[j].x) + unphi(gd[j].x);
        ci[2] = unplo(gs[j].y) + unplo(gd[j].y);
        ci[3] = unphi(gs[j].y) + unphi(gd[j].y);
        short8 aB;
        if (q < 3) aB = *(const short8*)(Btl + (t * 16 + m) * 24 + q * 8);
        else { union { short8 v; unsigned int u[4]; } z; z.u[0]=z.u[1]=z.u[2]=z.u[3]=0u; aB = z.v; }
        float4v o = __builtin_amdgcn_mfma_f32_16x16x32_bf16(aB, at.v, ci, 0, 0, 0);
        uint2 ov;
        ov.x = packtrunc(siluf(o[0]), siluf(o[1]));
        ov.y = packtrunc(siluf(o[2]), siluf(o[3]));
        *(uint2*)(S + m * 140 + t * 16 + q * 4) = ov;
      }
    }

    // layer-2 MFMA swapped: A = W2^T from LDS, B = u^T from S
    float4v c2[8];
    #pragma unroll
    for (int t = 0; t < 8; ++t) c2[t] = (float4v){0.f, 0.f, 0.f, 0.f};
    #pragma unroll
    for (int step = 0; step < 4; ++step){
      short8 bU = *(const short8*)(S + m * 140 + step * 32 + q * 8);
      #pragma unroll
      for (int t = 0; t < 8; ++t){
        short8 aW = *(const short8*)(W2t + (size_t)(t * 16 + m) * 136 + step * 32 + q * 8);
        c2[t] = __builtin_amdgcn_mfma_f32_16x16x32_bf16(aW, bU, c2[t], 0, 0, 0);
      }
    }

    // attention: lane holds edge m's n-values; 1 sigmoid/lane, 2-shfl reduce
    float p = 0.f;
    #pragma unroll
    for (int t = 0; t < 8; ++t){
      float4 bv = *(const float4*)(b2l + t * 16 + q * 4);
      float4 wv = *(const float4*)(wal + t * 16 + q * 4);
      c2[t][0] += bv.x; c2[t][1] += bv.y; c2[t][2] += bv.z; c2[t][3] += bv.w;
      p = fmaf(c2[t][0], wv.x, p); p = fmaf(c2[t][1], wv.y, p);
      p = fmaf(c2[t][2], wv.z, p); p = fmaf(c2[t][3], wv.w, p);
    }
    p += __shfl_xor(p, 16); p += __shfl_xor(p, 32);
    const float att = rcpf(1.f + __expf(-(p + attb)));
    #pragma unroll
    for (int t = 0; t < 8; ++t){
      uint2 ov;
      ov.x = packtrunc(att * c2[t][0], att * c2[t][1]);
      ov.y = packtrunc(att * c2[t][2], att * c2[t][3]);
      *(uint2*)(S + m * 140 + t * 16 + q * 4) = ov;
    }

    // segmented f32 reduction over sorted dsts; one pk atomic per run
    __builtin_amdgcn_sched_barrier(0);
    float a0 = 0.f, a1 = 0.f;
    int dp = __shfl(dmy, 0);
    #pragma unroll
    for (int half = 0; half < 2; ++half){
      unsigned int vv[8]; int dvr[8];
      #pragma unroll
      for (int j = 0; j < 8; ++j){
        const int eg = half * 8 + j;
        vv[j]  = *(const unsigned int*)(S + eg * 140 + lane * 2);
        dvr[j] = __shfl(dmy, eg);
      }
      #pragma unroll
      for (int j = 0; j < 8; ++j){
        if (dvr[j] != dp){                      // wave-uniform branch
          atomAddBF2(msg_agg + (size_t)dp * HD + lane * 2, packbf(a0, a1));
          a0 = a1 = 0.f; dp = dvr[j];
        }
        if (e0 + half * 8 + j < E){ a0 += unplo(vv[j]); a1 += unphi(vv[j]); }
      }
    }
    atomAddBF2(msg_agg + (size_t)dp * HD + lane * 2, packbf(a0, a1));
  }
}

// ---------------------------------------------------------------------------
// Kernel 3: coord path over dst-SORTED edges. Same v6 treatment.
// ---------------------------------------------------------------------------
__global__ void __launch_bounds__(512, 4) k_edge_coord(
    const int* __restrict__ ss, const int* __restrict__ ddv,
    const unsigned short* __restrict__ eaS, const float4* __restrict__ daux,
    const unsigned short* __restrict__ Axs, const unsigned short* __restrict__ Axd,
    const float* __restrict__ Wx_w1, const float* __restrict__ Wx_w2,
    const float* __restrict__ Wx_b2, const float* __restrict__ Wx_w3,
    float* __restrict__ xout, int E)
{
  __shared__ __align__(16) unsigned short W2t[128 * 136];   // 34816 B
  __shared__ __align__(16) unsigned short Btl[128 * 16];    // 4096 B [col][k<16]
  __shared__ __align__(16) unsigned short Ssh[8][16 * 140]; // 35840 B
  __shared__ __align__(16) float b2l[128];                  // 512 B
  __shared__ __align__(16) float w3l[128];                  // 512 B
  // total 75776 B -> 2 blocks/CU

  const int tid = threadIdx.x;
  for (int i = tid; i < 128 * 128; i += 512){
    int col = i & 127, k = i >> 7;
    W2t[col * 136 + k] = f2b(Wx_w2[k * 128 + col]);
  }
  for (int i = tid; i < 128 * 16; i += 512){
    int col = i >> 4, k = i & 15;
    Btl[col * 16 + k] = f2b(Wx_w1[(256 + k) * 128 + col]);
  }
  for (int i = tid; i < 128; i += 512){ b2l[i] = Wx_b2[i]; w3l[i] = Wx_w3[i]; }
  __syncthreads();

  const int lane = tid & 63, w = tid >> 6;
  const int m = lane & 15, q = lane >> 4;
  unsigned short* S = Ssh[w];

  const int tiles = (E + 15) >> 4;
  const int wid = blockIdx.x * 8 + w;
  const int nwv = gridDim.x * 8;

  for (int tb = wid; tb < tiles; tb += nwv){
    const int e0 = tb << 4;

    int smy = 0, dmy = 0;
    float dxv = 0.f, dyv = 0.f, dzv = 0.f, rsv = 0.f;
    if (lane < 16){
      const int eC = min(e0 + lane, E - 1);
      smy = ss[eC]; dmy = ddv[eC];
      float4 d4 = daux[eC];
      dxv = d4.x; dyv = d4.y; dzv = d4.z;
      rsv = 2.5f * rcpf(sqrtf(d4.w + 1e-8f) + 1.0f);
    }
    const int s_m = __shfl(smy, m), d_m = __shfl(dmy, m);
    const float dxm = __shfl(dxv, m), dym = __shfl(dyv, m);
    const float dzm = __shfl(dzv, m), rsm = __shfl(rsv, m);

    // tail B-frag (ea only, k<16)
    union { short8 v; unsigned int u[4]; } at;
    at.u[0] = at.u[1] = at.u[2] = at.u[3] = 0u;
    if (q < 2)
      at.v = *(const short8*)(eaS + (size_t)min(e0 + m, E - 1) * 16 + q * 8);

    const unsigned short* pS = Axs + (size_t)s_m * HD + q * 4;
    const unsigned short* pD = Axd + (size_t)d_m * HD + q * 4;

    #pragma unroll
    for (int ph = 0; ph < 2; ++ph){
      uint2 gs[4], gd[4];
      #pragma unroll
      for (int j = 0; j < 4; ++j){
        gs[j] = *(const uint2*)(pS + (ph * 4 + j) * 16);
        gd[j] = *(const uint2*)(pD + (ph * 4 + j) * 16);
      }
      #pragma unroll
      for (int j = 0; j < 4; ++j){
        const int t = ph * 4 + j;
        float4v ci;
        ci[0] = unplo(gs[j].x) + unplo(gd[j].x);
        ci[1] = unphi(gs[j].x) + unphi(gd[j].x);
        ci[2] = unplo(gs[j].y) + unplo(gd[j].y);
        ci[3] = unphi(gs[j].y) + unphi(gd[j].y);
        short8 aB;
        if (q < 2) aB = *(const short8*)(Btl + (t * 16 + m) * 16 + q * 8);
        else { union { short8 v; unsigned int u[4]; } z; z.u[0]=z.u[1]=z.u[2]=z.u[3]=0u; aB = z.v; }
        float4v o = __builtin_amdgcn_mfma_f32_16x16x32_bf16(aB, at.v, ci, 0, 0, 0);
        uint2 ov;
        ov.x = packtrunc(siluf(o[0]), siluf(o[1]));
        ov.y = packtrunc(siluf(o[2]), siluf(o[3]));
        *(uint2*)(S + m * 140 + t * 16 + q * 4) = ov;
      }
    }

    float4v c2[8];
    #pragma unroll
    for (int t = 0; t < 8; ++t) c2[t] = (float4v){0.f, 0.f, 0.f, 0.f};
    #pragma unroll
    for (int step = 0; step < 4; ++step){
      short8 bU = *(const short8*)(S + m * 140 + step * 32 + q * 8);
      #pragma unroll
      for (int t = 0; t < 8; ++t){
        short8 aW = *(const short8*)(W2t + (size_t)(t * 16 + m) * 136 + step * 32 + q * 8);
        c2[t] = __builtin_amdgcn_mfma_f32_16x16x32_bf16(aW, bU, c2[t], 0, 0, 0);
      }
    }

    // coord weight: lane holds edge m; 1 tanh/lane via exp+rcp
    float p = 0.f;
    #pragma unroll
    for (int t = 0; t < 8; ++t){
      float4 bv = *(const float4*)(b2l + t * 16 + q * 4);
      float4 wv = *(const float4*)(w3l + t * 16 + q * 4);
      p = fmaf(siluf(c2[t][0] + bv.x), wv.x, p);
      p = fmaf(siluf(c2[t][1] + bv.y), wv.y, p);
      p = fmaf(siluf(c2[t][2] + bv.z), wv.z, p);
      p = fmaf(siluf(c2[t][3] + bv.w), wv.w, p);
    }
    p += __shfl_xor(p, 16); p += __shfl_xor(p, 32);
    const float th = 1.f - 2.f * rcpf(1.f + __expf(2.f * p));  // tanh(p)
    const float sc = th * rsm;
    const float comp = (q == 0) ? dxm : (q == 1) ? dym : dzm;
    const float contrib = comp * sc;   // meaningful for q<3

    // segmented emit: lanes 0..2 emit; contributions pulled via shfl
    __builtin_amdgcn_sched_barrier(0);
    int dp = __shfl(dmy, 0); float acc = 0.f;
    #pragma unroll
    for (int eg = 0; eg < 16; ++eg){
      int dc = __shfl(dmy, eg);
      float c = __shfl(contrib, ((lane & 3) << 4) + eg);
      if (dc != dp){                               // wave-uniform
        if (lane < 3) atomAddF(xout + (size_t)dp * 3 + lane, acc);
        acc = 0.f; dp = dc;
      }
      if (e0 + eg < E) acc += c;
    }
    if (lane < 3) atomAddF(xout + (size_t)dp * 3 + lane, acc);
  }
}

// ---------------------------------------------------------------------------
// Kernel 4: z2 = bf16( silu( zpre + msg @ Wh_w1[128:256] ) ) — msg bf16.
// ---------------------------------------------------------------------------
__global__ void __launch_bounds__(256) k_h1b2(
    const unsigned short* __restrict__ msg, const unsigned short* __restrict__ zpre,
    const float* __restrict__ Wh_w1, unsigned short* __restrict__ z2, int N)
{
  __shared__ unsigned short Wt[128 * 136];
  __shared__ unsigned short OutS[64 * 136];

  for (int i = threadIdx.x; i < 128 * 128; i += 256){
    int k = i >> 7, col = i & 127;
    Wt[col * 136 + k] = f2b(Wh_w1[(128 + k) * 128 + col]);
  }
  __syncthreads();

  const int lane = threadIdx.x & 63, w = threadIdx.x >> 6;
  const int m = lane & 15, q = lane >> 4;

  const int ntiles = (N + 63) >> 6;
  for (int tile = blockIdx.x; tile < ntiles; tile += gridDim.x){
    const int n0 = tile << 6;
    const int n = min(n0 + w * 16 + m, N - 1);

    short8 a[4];
    #pragma unroll
    for (int step = 0; step < 4; ++step)
      a[step] = *(const short8*)(msg + (size_t)n * 128 + step * 32 + q * 8);

    float4v acc[8];
    #pragma unroll
    for (int t = 0; t < 8; ++t) acc[t] = (float4v){0.f, 0.f, 0.f, 0.f};
    #pragma unroll
    for (int step = 0; step < 4; ++step){
      #pragma unroll
      for (int t = 0; t < 8; ++t){
        short8 b = *(const short8*)(Wt + (size_t)(t * 16 + m) * 136 + step * 32 + q * 8);
        acc[t] = __builtin_amdgcn_mfma_f32_16x16x32_bf16(a[step], b, acc[t], 0, 0, 0);
      }
    }

    #pragma unroll
    for (int t = 0; t < 8; ++t)
      #pragma unroll
      for (int r = 0; r < 4; ++r)
        OutS[(w * 16 + q * 4 + r) * 136 + t * 16 + m] = f2b(acc[t][r]);
    __syncthreads();
    for (int i = threadIdx.x; i < 64 * 16; i += 256){
      int node = i >> 4, seg = i & 15;
      int nn = n0 + node;
      if (nn < N){
        uint4 dv = *(const uint4*)(OutS + node * 136 + seg * 8);
        uint4 zv = *(const uint4*)(zpre + (size_t)nn * 128 + seg * 8);
        float fd[8], fz[8];
        unp8(dv, fd); unp8(zv, fz);
        uint4 ov;
        ov.x = packbf(siluf(fz[0] + fd[0]), siluf(fz[1] + fd[1]));
        ov.y = packbf(siluf(fz[2] + fd[2]), siluf(fz[3] + fd[3]));
        ov.z = packbf(siluf(fz[4] + fd[4]), siluf(fz[5] + fd[5]));
        ov.w = packbf(siluf(fz[6] + fd[6]), siluf(fz[7] + fd[7]));
        *(uint4*)(z2 + (size_t)nn * 128 + seg * 8) = ov;
      }
    }
    __syncthreads();
  }
}

// ---------------------------------------------------------------------------
// Kernel 5: hout = h + z2 @ Wh_w2 + Wh_b2
// ---------------------------------------------------------------------------
__global__ void __launch_bounds__(256) k_h22(
    const float* __restrict__ h, const unsigned short* __restrict__ z2,
    const float* __restrict__ Wh_w2, const float* __restrict__ Wh_b2,
    float* __restrict__ hout, int N)
{
  __shared__ unsigned short Wt[128 * 136];
  __shared__ float OutSf[64 * 132];

  for (int i = threadIdx.x; i < 128 * 128; i += 256){
    int k = i >> 7, col = i & 127;
    Wt[col * 136 + k] = f2b(Wh_w2[k * 128 + col]);
  }
  __syncthreads();

  const int lane = threadIdx.x & 63, w = threadIdx.x >> 6;
  const int m = lane & 15, q = lane >> 4;
  float bb[8];
  #pragma unroll
  for (int t = 0; t < 8; ++t) bb[t] = Wh_b2[t * 16 + m];

  const int ntiles = (N + 63) >> 6;
  for (int tile = blockIdx.x; tile < ntiles; tile += gridDim.x){
    const int n0 = tile << 6;
    const int n = min(n0 + w * 16 + m, N - 1);

    short8 a[4];
    #pragma unroll
    for (int step = 0; step < 4; ++step)
      a[step] = *(const short8*)(z2 + (size_t)n * 128 + step * 32 + q * 8);

    float4v acc[8];
    #pragma unroll
    for (int t = 0; t < 8; ++t) acc[t] = (float4v){0.f, 0.f, 0.f, 0.f};
    #pragma unroll
    for (int step = 0; step < 4; ++step){
      #pragma unroll
      for (int t = 0; t < 8; ++t){
        short8 b = *(const short8*)(Wt + (size_t)(t * 16 + m) * 136 + step * 32 + q * 8);
        acc[t] = __builtin_amdgcn_mfma_f32_16x16x32_bf16(a[step], b, acc[t], 0, 0, 0);
      }
    }

    #pragma unroll
    for (int t = 0; t < 8; ++t)
      #pragma unroll
      for (int r = 0; r < 4; ++r)
        OutSf[(w * 16 + q * 4 + r) * 132 + t * 16 + m] = acc[t][r] + bb[t];
    __syncthreads();
    for (int i = threadIdx.x; i < 64 * 32; i += 256){
      int node = i >> 5, seg = i & 31;
      int nn = n0 + node;
      if (nn < N){
        float4 dv = *(const float4*)(OutSf + node * 132 + seg * 4);
        float4 hv = *(const float4*)(h + (size_t)nn * 128 + seg * 4);
        float4 ov = {hv.x + dv.x, hv.y + dv.y, hv.z + dv.z, hv.w + dv.w};
        *(float4*)(hout + (size_t)nn * 128 + seg * 4) = ov;
      }
    }
    __syncthreads();
  }
}

extern "C" void kernel_launch(void* const* d_in, const int* in_sizes, int n_in,
                              void* d_out, int out_size, void* d_ws, size_t ws_size,
                              hipStream_t stream)
{
  const float* h      = (const float*)d_in[0];
  const float* x      = (const float*)d_in[1];
  const int*   ei     = (const int*)  d_in[2];
  const float* ea     = (const float*)d_in[3];
  const float* t_emb  = (const float*)d_in[4];
  const float* We_w1  = (const float*)d_in[5];
  const float* We_b1  = (const float*)d_in[6];
  const float* We_w2  = (const float*)d_in[7];
  const float* We_b2  = (const float*)d_in[8];
  const float* Watt_w = (const float*)d_in[9];
  const float* Watt_b = (const float*)d_in[10];
  const float* Wx_w1  = (const float*)d_in[11];
  const float* Wx_b1  = (const float*)d_in[12];
  const float* Wx_w2  = (const float*)d_in[13];
  const float* Wx_b2  = (const float*)d_in[14];
  const float* Wx_w3  = (const float*)d_in[15];
  const float* Wh_w1  = (const float*)d_in[16];
  const float* Wh_b1  = (const float*)d_in[17];
  const float* Wh_w2  = (const float*)d_in[18];
  const float* Wh_b2  = (const float*)d_in[19];

  const int N = in_sizes[0] / HD;
  const int E = in_sizes[2] / 2;

  char* ws = (char*)d_ws;
  unsigned short* Aes  = (unsigned short*)ws;  ws += (size_t)N * HD * 2;
  unsigned short* Aed  = (unsigned short*)ws;  ws += (size_t)N * HD * 2;
  unsigned short* Axs  = (unsigned short*)ws;  ws += (size_t)N * HD * 2;
  unsigned short* Axd  = (unsigned short*)ws;  ws += (size_t)N * HD * 2;
  unsigned short* zpre = (unsigned short*)ws;  ws += (size_t)N * HD * 2;
  unsigned short* z2   = (unsigned short*)ws;  ws += (size_t)N * HD * 2;
  unsigned short* msg_agg = (unsigned short*)ws; ws += (size_t)N * HD * 2;
  unsigned short* hb   = (unsigned short*)ws;  ws += (size_t)N * HD * 2;
  unsigned short* tb   = (unsigned short*)ws;  ws += (size_t)N * TD * 2;

  // Overlays into [hb .. hb+16MB) AFTER k_pre2 consumed hb/tb:
  //   ss (E ints) | ddv (E ints) | daux (E float4) = 24E = 14.4MB <= 16MB
  char* sortbase = (char*)hb;
  int*    ss_   = (int*)sortbase;
  int*    ddv_  = ss_ + E;
  float4* daux_ = (float4*)(sortbase + (size_t)8 * E);
  // cnt/off live in msg_agg's first 2N ints during sort (re-zeroed after)
  int* cnt_ = (int*)msg_agg;
  int* off_ = cnt_ + N;

  float* hout = (float*)d_out;
  float* xout = hout + (size_t)N * HD;
  // eaS (E x 16 bf16, sorted order) borrows hout space; k_h22 (last kernel)
  // fully overwrites hout afterwards. Stream order guarantees safety.
  unsigned short* eaS_ = (unsigned short*)hout;

  hipMemsetAsync(msg_agg, 0, (size_t)N * HD * 2, stream);   // also zeroes cnt/off
  hipMemcpyAsync(xout, x, (size_t)N * 3 * 4, hipMemcpyDeviceToDevice, stream);

  k_cvt<<<400, 256, 0, stream>>>(h, hb, N * (HD / 8));
  k_cvt<<<100, 256, 0, stream>>>(t_emb, tb, N * (TD / 8));

  dim3 gP(192, 5);
  k_pre2<<<gP, 256, 0, stream>>>(hb, tb, We_w1, We_b1, Wx_w1, Wx_b1,
                                 Wh_w1, Wh_b1, Aes, Aed, Axs, Axd, zpre, N);

  // counting sort by dst + per-edge precompute (hb/tb free after k_pre2)
  k_hist<<<512, 256, 0, stream>>>(ei, cnt_, E);
  k_scan<<<1, 1024, 0, stream>>>(cnt_, off_, N);
  k_scatter<<<1024, 256, 0, stream>>>(ei, x, ea, off_, ss_, ddv_, daux_, eaS_, E);

  // re-zero the msg_agg area that hosted cnt/off
  hipMemsetAsync(msg_agg, 0, (size_t)2 * N * sizeof(int), stream);

  k_edge_msg<<<512, 512, 0, stream>>>(ss_, ddv_, eaS_, daux_, Aes, Aed,
                                      We_w1, We_w2, We_b2, Watt_w, Watt_b,
                                      msg_agg, E);
  k_edge_coord<<<512, 512, 0, stream>>>(ss_, ddv_, eaS_, daux_, Axs, Axd,
                                        Wx_w1, Wx_w2, Wx_b2, Wx_w3, xout, E);
  k_h1b2<<<512, 256, 0, stream>>>(msg_agg, zpre, Wh_w1, z2, N);
  k_h22<<<512, 256, 0, stream>>>(h, z2, Wh_w2, Wh_b2, hout, N);
}

// Round 8
// 518.471 us; speedup vs baseline: 2.8549x; 1.1138x over previous
//
#include <hip/hip_runtime.h>
#include <hip/hip_bf16.h>

#define HD 128
#define ED 16
#define TD 32

typedef __attribute__((ext_vector_type(8))) short short8;
typedef __attribute__((ext_vector_type(4))) float float4v;

__device__ __forceinline__ float rcpf(float x){ return __builtin_amdgcn_rcpf(x); }
__device__ __forceinline__ float siluf(float v){ return v * rcpf(1.0f + __expf(-v)); }

// bf16 pack/unpack helpers
__device__ __forceinline__ unsigned int bfbits(float x){          // RTNE
  unsigned int a = __float_as_uint(x);
  return (a + 0x7fffu + ((a >> 16) & 1u)) >> 16;
}
__device__ __forceinline__ unsigned int packbf(float lo, float hi){  // RTNE pair
  return (bfbits(lo) & 0xffffu) | (bfbits(hi) << 16);
}
// 1-op truncation pack via v_perm_b32: [lo.b2, lo.b3, hi.b2, hi.b3]
__device__ __forceinline__ unsigned int packtrunc(float lo, float hi){
  return __builtin_amdgcn_perm(__float_as_uint(hi), __float_as_uint(lo), 0x07060302u);
}
__device__ __forceinline__ float unplo(unsigned int w){ return __uint_as_float(w << 16); }
__device__ __forceinline__ float unphi(unsigned int w){ return __uint_as_float(w & 0xffff0000u); }
__device__ __forceinline__ unsigned short f2b(float x){ return (unsigned short)bfbits(x); }

__device__ __forceinline__ void unp8(uint4 u, float* f){
  f[0]=unplo(u.x); f[1]=unphi(u.x); f[2]=unplo(u.y); f[3]=unphi(u.y);
  f[4]=unplo(u.z); f[5]=unphi(u.z); f[6]=unplo(u.w); f[7]=unphi(u.w);
}

__device__ __forceinline__ void atomAddF(float* p, float v){
  unsafeAtomicAdd(p, v);  // HW global_atomic_add_f32 on gfx950
}

// packed bf16 atomic add: one instruction adds 2 bf16 lanes-worth
__device__ __forceinline__ void atomAddBF2(unsigned short* p, unsigned int packed){
  asm volatile("global_atomic_pk_add_bf16 %0, %1, off"
               :: "v"((unsigned long long)(uintptr_t)p), "v"(packed) : "memory");
}

// ---------------------------------------------------------------------------
// Kernel 0: fp32 -> bf16 (RTNE) stream convert, 8 elems/thread-iter.
// ---------------------------------------------------------------------------
__global__ void __launch_bounds__(256) k_cvt(
    const float* __restrict__ src, unsigned short* __restrict__ dst, int n8)
{
  for (int i = blockIdx.x * 256 + threadIdx.x; i < n8; i += gridDim.x * 256){
    float4 v0 = *(const float4*)(src + (size_t)i * 8);
    float4 v1 = *(const float4*)(src + (size_t)i * 8 + 4);
    uint4 o;
    o.x = packbf(v0.x, v0.y); o.y = packbf(v0.z, v0.w);
    o.z = packbf(v1.x, v1.y); o.w = packbf(v1.z, v1.w);
    *(uint4*)(dst + (size_t)i * 8) = o;
  }
}

// ---------------------------------------------------------------------------
// Sort-by-dst preprocessing: hist -> scan -> scatter.
// k_scatter hoists per-edge scalar work: daux = (dx,dy,dz,dist),
// eaS = edge_attr in sorted order as bf16.
// ---------------------------------------------------------------------------
__global__ void __launch_bounds__(256) k_hist(
    const int* __restrict__ ei, int* __restrict__ cnt, int E)
{
  for (int e = blockIdx.x * 256 + threadIdx.x; e < E; e += gridDim.x * 256)
    atomicAdd(&cnt[ei[E + e]], 1);
}

__global__ void __launch_bounds__(1024) k_scan(
    const int* __restrict__ cnt, int* __restrict__ off, int n)
{
  const int tid = threadIdx.x, lane = tid & 63, wv = tid >> 6;  // 16 waves
  __shared__ int wsum[16];
  __shared__ int carryS;
  if (tid == 0) carryS = 0;
  __syncthreads();
  const int CH = 1024 * 8;
  for (int base = 0; base < n; base += CH){
    const int idx0 = base + tid * 8;
    int v[8];
    #pragma unroll
    for (int j = 0; j < 8; ++j){ int i = idx0 + j; v[j] = (i < n) ? cnt[i] : 0; }
    #pragma unroll
    for (int j = 1; j < 8; ++j) v[j] += v[j - 1];   // local inclusive
    const int tot = v[7];
    int sc = tot;                                    // wave inclusive scan
    #pragma unroll
    for (int d = 1; d < 64; d <<= 1){ int t = __shfl_up(sc, d); if (lane >= d) sc += t; }
    if (lane == 63) wsum[wv] = sc;
    __syncthreads();
    if (tid < 16){
      int s = wsum[tid];
      #pragma unroll
      for (int d = 1; d < 16; d <<= 1){ int t = __shfl_up(s, d); if (tid >= d) s += t; }
      wsum[tid] = s;
    }
    __syncthreads();
    const int base_excl = carryS + (wv > 0 ? wsum[wv - 1] : 0) + (sc - tot);
    #pragma unroll
    for (int j = 0; j < 8; ++j){
      int i = idx0 + j;
      if (i < n) off[i] = base_excl + (j > 0 ? v[j - 1] : 0);
    }
    __syncthreads();
    if (tid == 0) carryS += wsum[15];
    __syncthreads();
  }
}

__global__ void __launch_bounds__(256) k_scatter(
    const int* __restrict__ ei, const float* __restrict__ x,
    const float* __restrict__ ea, int* __restrict__ off,
    int* __restrict__ ss, int* __restrict__ ddv,
    float4* __restrict__ daux, unsigned short* __restrict__ eaS, int E)
{
  for (int e = blockIdx.x * 256 + threadIdx.x; e < E; e += gridDim.x * 256){
    int s = ei[e], d = ei[E + e];
    int pos = atomicAdd(&off[d], 1);
    ss[pos] = s; ddv[pos] = d;
    float dx = x[s * 3 + 0] - x[d * 3 + 0];
    float dy = x[s * 3 + 1] - x[d * 3 + 1];
    float dz = x[s * 3 + 2] - x[d * 3 + 2];
    float4 da; da.x = dx; da.y = dy; da.z = dz; da.w = dx*dx + dy*dy + dz*dz;
    daux[pos] = da;
    const float4* e4 = (const float4*)(ea + (size_t)e * ED);
    float4 a = e4[0], b = e4[1], c = e4[2], dd = e4[3];
    uint4 o1, o2;
    o1.x = packtrunc(a.x, a.y); o1.y = packtrunc(a.z, a.w);
    o1.z = packtrunc(b.x, b.y); o1.w = packtrunc(b.z, b.w);
    o2.x = packtrunc(c.x, c.y); o2.y = packtrunc(c.z, c.w);
    o2.z = packtrunc(dd.x, dd.y); o2.w = packtrunc(dd.z, dd.w);
    *(uint4*)(eaS + (size_t)pos * 16) = o1;
    *(uint4*)(eaS + (size_t)pos * 16 + 8) = o2;
  }
}

// ---------------------------------------------------------------------------
// Kernel 1: node-side first-layer GEMMs via MFMA. v7: 512 threads,
// 128-node tiles -> LDS 77.8KB, 2 blocks/CU = 16 waves/CU (4/SIMD, was 2).
// ---------------------------------------------------------------------------
__global__ void __launch_bounds__(512) k_pre2(
    const unsigned short* __restrict__ hb, const unsigned short* __restrict__ tb,
    const float* __restrict__ We_w1, const float* __restrict__ We_b1,
    const float* __restrict__ Wx_w1, const float* __restrict__ Wx_b1,
    const float* __restrict__ Wh_w1, const float* __restrict__ Wh_b1,
    unsigned short* __restrict__ Aes, unsigned short* __restrict__ Aed,
    unsigned short* __restrict__ Axs, unsigned short* __restrict__ Axd,
    unsigned short* __restrict__ zpre, int N)
{
  __shared__ unsigned short Wt[128 * 168];     // 43008 B
  __shared__ unsigned short OutS[128 * 136];   // 34816 B -> total 77824 B

  const int group = blockIdx.y;
  const float* Wsrc = (group <= 1) ? We_w1 : (group <= 3) ? Wx_w1 : Wh_w1;
  const float* bias = (group == 0) ? We_b1 : (group == 2) ? Wx_b1
                    : (group == 4) ? Wh_b1 : nullptr;
  unsigned short* out = (group == 0) ? Aes : (group == 1) ? Aed
                      : (group == 2) ? Axs : (group == 3) ? Axd : zpre;
  const int rowBase = (group == 1 || group == 3) ? 128 : 0;
  const int tBase   = (group == 0) ? 273 : (group == 2) ? 272 : -1;

  for (int i = threadIdx.x; i < 160 * 128; i += 512){
    int k = i >> 7, col = i & 127;
    float wv = 0.f;
    if (k < 128)      wv = Wsrc[(rowBase + k) * 128 + col];
    else if (tBase >= 0) wv = Wsrc[(tBase + (k - 128)) * 128 + col];
    Wt[col * 168 + k] = f2b(wv);
  }
  __syncthreads();

  const int lane = threadIdx.x & 63, w = threadIdx.x >> 6;   // w = 0..7
  const int m = lane & 15, q = lane >> 4;
  float bb[8];
  #pragma unroll
  for (int t = 0; t < 8; ++t) bb[t] = bias ? bias[t * 16 + m] : 0.f;

  const int ntiles = (N + 127) >> 7;
  for (int tile = blockIdx.x; tile < ntiles; tile += gridDim.x){
    const int n0 = tile << 7;
    const int n = min(n0 + w * 16 + m, N - 1);

    short8 a[5];
    #pragma unroll
    for (int step = 0; step < 4; ++step)
      a[step] = *(const short8*)(hb + (size_t)n * 128 + step * 32 + q * 8);
    a[4] = *(const short8*)(tb + (size_t)n * 32 + q * 8);

    float4v acc[8];
    #pragma unroll
    for (int t = 0; t < 8; ++t) acc[t] = (float4v){0.f, 0.f, 0.f, 0.f};
    #pragma unroll
    for (int step = 0; step < 5; ++step){
      #pragma unroll
      for (int t = 0; t < 8; ++t){
        short8 b = *(const short8*)(Wt + (size_t)(t * 16 + m) * 168 + step * 32 + q * 8);
        acc[t] = __builtin_amdgcn_mfma_f32_16x16x32_bf16(a[step], b, acc[t], 0, 0, 0);
      }
    }

    #pragma unroll
    for (int t = 0; t < 8; ++t)
      #pragma unroll
      for (int r = 0; r < 4; ++r)
        OutS[(w * 16 + q * 4 + r) * 136 + t * 16 + m] = f2b(acc[t][r] + bb[t]);
    __syncthreads();
    for (int i = threadIdx.x; i < 128 * 16; i += 512){
      int node = i >> 4, seg = i & 15;
      int nn = n0 + node;
      if (nn < N)
        *(uint4*)(out + (size_t)nn * 128 + seg * 8) =
            *(const uint4*)(OutS + node * 136 + seg * 8);
    }
    __syncthreads();
  }
}

// ---------------------------------------------------------------------------
// Kernel 2: message path over dst-SORTED edges (r6 structure, frozen).
// ---------------------------------------------------------------------------
__global__ void __launch_bounds__(512, 4) k_edge_msg(
    const int* __restrict__ ss, const int* __restrict__ ddv,
    const unsigned short* __restrict__ eaS, const float4* __restrict__ daux,
    const unsigned short* __restrict__ Aes, const unsigned short* __restrict__ Aed,
    const float* __restrict__ We_w1, const float* __restrict__ We_w2,
    const float* __restrict__ We_b2, const float* __restrict__ Watt_w,
    const float* __restrict__ Watt_b,
    unsigned short* __restrict__ msg_agg, int E)
{
  __shared__ __align__(16) unsigned short W2t[128 * 136];   // 34816 B [col][k]
  __shared__ __align__(16) unsigned short Btl[128 * 24];    // 6144 B  [col][k<24]
  __shared__ __align__(16) unsigned short Ssh[8][16 * 140]; // 35840 B [edge][n]
  __shared__ __align__(16) float b2l[128];                  // 512 B
  __shared__ __align__(16) float wal[128];                  // 512 B
  // total 77824 B -> 2 blocks/CU (16 waves)

  const int tid = threadIdx.x;
  for (int i = tid; i < 128 * 128; i += 512){
    int col = i & 127, k = i >> 7;
    W2t[col * 136 + k] = f2b(We_w2[k * 128 + col]);
  }
  for (int i = tid; i < 128 * 24; i += 512){
    int col = i / 24, k = i % 24;
    float wv = (k < 16) ? We_w1[(257 + k) * 128 + col]
             : (k == 16 ? We_w1[256 * 128 + col] : 0.f);
    Btl[col * 24 + k] = f2b(wv);
  }
  for (int i = tid; i < 128; i += 512){ b2l[i] = We_b2[i]; wal[i] = Watt_w[i]; }
  __syncthreads();

  const int lane = tid & 63, w = tid >> 6;
  const int m = lane & 15, q = lane >> 4;
  const float attb = Watt_b[0];
  unsigned short* S = Ssh[w];

  const int tiles = (E + 15) >> 4;
  const int wid = blockIdx.x * 8 + w;
  const int nwv = gridDim.x * 8;

  for (int tb = wid; tb < tiles; tb += nwv){
    const int e0 = tb << 4;

    // per-edge indices/scalars (lanes 0..15), distributed via shfl
    int smy = 0, dmy = 0; float dval = 0.f;
    if (lane < 16){
      const int eC = min(e0 + lane, E - 1);
      smy = ss[eC]; dmy = ddv[eC]; dval = daux[eC].w;
    }
    const int s_m = __shfl(smy, m), d_m = __shfl(dmy, m);
    const float dm = __shfl(dval, m);

    // tail B-frag: lane = edge m, k-slice q*8; k<16 = ea, k==16 = dist
    union { short8 v; unsigned int u[4]; } at;
    at.u[0] = at.u[1] = at.u[2] = at.u[3] = 0u;
    if (q < 2){
      at.v = *(const short8*)(eaS + (size_t)min(e0 + m, E - 1) * 16 + q * 8);
    } else if (q == 2){
      at.u[0] = __float_as_uint(dm) >> 16;
    }

    // direct C-layout gather bases (lane owns edge m, n-offsets t*16+q*4)
    const unsigned short* pS = Aes + (size_t)s_m * HD + q * 4;
    const unsigned short* pD = Aed + (size_t)d_m * HD + q * 4;

    // tail MFMA swapped, 2 phases of 4 t's; C = f32 sum of gathers; silu->S
    #pragma unroll
    for (int ph = 0; ph < 2; ++ph){
      uint2 gs[4], gd[4];
      #pragma unroll
      for (int j = 0; j < 4; ++j){
        gs[j] = *(const uint2*)(pS + (ph * 4 + j) * 16);
        gd[j] = *(const uint2*)(pD + (ph * 4 + j) * 16);
      }
      #pragma unroll
      for (int j = 0; j < 4; ++j){
        const int t = ph * 4 + j;
        float4v ci;
        ci[0] = unplo(gs[j].x) + unplo(gd[j].x);
        ci[1] = unphi(gs[j].x) + unphi(gd[j].x);
        ci[2] = unplo(gs[j].y) + unplo(gd[j].y);
        ci[3] = unphi(gs[j].y) + unphi(gd[j].y);
        short8 aB;
        if (q < 3) aB = *(const short8*)(Btl + (t * 16 + m) * 24 + q * 8);
        else { union { short8 v; unsigned int u[4]; } z; z.u[0]=z.u[1]=z.u[2]=z.u[3]=0u; aB = z.v; }
        float4v o = __builtin_amdgcn_mfma_f32_16x16x32_bf16(aB, at.v, ci, 0, 0, 0);
        uint2 ov;
        ov.x = packtrunc(siluf(o[0]), siluf(o[1]));
        ov.y = packtrunc(siluf(o[2]), siluf(o[3]));
        *(uint2*)(S + m * 140 + t * 16 + q * 4) = ov;
      }
    }

    // layer-2 MFMA swapped: A = W2^T from LDS, B = u^T from S
    float4v c2[8];
    #pragma unroll
    for (int t = 0; t < 8; ++t) c2[t] = (float4v){0.f, 0.f, 0.f, 0.f};
    #pragma unroll
    for (int step = 0; step < 4; ++step){
      short8 bU = *(const short8*)(S + m * 140 + step * 32 + q * 8);
      #pragma unroll
      for (int t = 0; t < 8; ++t){
        short8 aW = *(const short8*)(W2t + (size_t)(t * 16 + m) * 136 + step * 32 + q * 8);
        c2[t] = __builtin_amdgcn_mfma_f32_16x16x32_bf16(aW, bU, c2[t], 0, 0, 0);
      }
    }

    // attention: lane holds edge m's n-values; 1 sigmoid/lane, 2-shfl reduce
    float p = 0.f;
    #pragma unroll
    for (int t = 0; t < 8; ++t){
      float4 bv = *(const float4*)(b2l + t * 16 + q * 4);
      float4 wv = *(const float4*)(wal + t * 16 + q * 4);
      c2[t][0] += bv.x; c2[t][1] += bv.y; c2[t][2] += bv.z; c2[t][3] += bv.w;
      p = fmaf(c2[t][0], wv.x, p); p = fmaf(c2[t][1], wv.y, p);
      p = fmaf(c2[t][2], wv.z, p); p = fmaf(c2[t][3], wv.w, p);
    }
    p += __shfl_xor(p, 16); p += __shfl_xor(p, 32);
    const float att = rcpf(1.f + __expf(-(p + attb)));
    #pragma unroll
    for (int t = 0; t < 8; ++t){
      uint2 ov;
      ov.x = packtrunc(att * c2[t][0], att * c2[t][1]);
      ov.y = packtrunc(att * c2[t][2], att * c2[t][3]);
      *(uint2*)(S + m * 140 + t * 16 + q * 4) = ov;
    }

    // segmented f32 reduction over sorted dsts; one pk atomic per run
    __builtin_amdgcn_sched_barrier(0);
    float a0 = 0.f, a1 = 0.f;
    int dp = __shfl(dmy, 0);
    #pragma unroll
    for (int half = 0; half < 2; ++half){
      unsigned int vv[8]; int dvr[8];
      #pragma unroll
      for (int j = 0; j < 8; ++j){
        const int eg = half * 8 + j;
        vv[j]  = *(const unsigned int*)(S + eg * 140 + lane * 2);
        dvr[j] = __shfl(dmy, eg);
      }
      #pragma unroll
      for (int j = 0; j < 8; ++j){
        if (dvr[j] != dp){                      // wave-uniform branch
          atomAddBF2(msg_agg + (size_t)dp * HD + lane * 2, packbf(a0, a1));
          a0 = a1 = 0.f; dp = dvr[j];
        }
        if (e0 + half * 8 + j < E){ a0 += unplo(vv[j]); a1 += unphi(vv[j]); }
      }
    }
    atomAddBF2(msg_agg + (size_t)dp * HD + lane * 2, packbf(a0, a1));
  }
}

// ---------------------------------------------------------------------------
// Kernel 3: coord path over dst-SORTED edges (r6 structure, frozen).
// ---------------------------------------------------------------------------
__global__ void __launch_bounds__(512, 4) k_edge_coord(
    const int* __restrict__ ss, const int* __restrict__ ddv,
    const unsigned short* __restrict__ eaS, const float4* __restrict__ daux,
    const unsigned short* __restrict__ Axs, const unsigned short* __restrict__ Axd,
    const float* __restrict__ Wx_w1, const float* __restrict__ Wx_w2,
    const float* __restrict__ Wx_b2, const float* __restrict__ Wx_w3,
    float* __restrict__ xout, int E)
{
  __shared__ __align__(16) unsigned short W2t[128 * 136];   // 34816 B
  __shared__ __align__(16) unsigned short Btl[128 * 16];    // 4096 B [col][k<16]
  __shared__ __align__(16) unsigned short Ssh[8][16 * 140]; // 35840 B
  __shared__ __align__(16) float b2l[128];                  // 512 B
  __shared__ __align__(16) float w3l[128];                  // 512 B
  // total 75776 B -> 2 blocks/CU

  const int tid = threadIdx.x;
  for (int i = tid; i < 128 * 128; i += 512){
    int col = i & 127, k = i >> 7;
    W2t[col * 136 + k] = f2b(Wx_w2[k * 128 + col]);
  }
  for (int i = tid; i < 128 * 16; i += 512){
    int col = i >> 4, k = i & 15;
    Btl[col * 16 + k] = f2b(Wx_w1[(256 + k) * 128 + col]);
  }
  for (int i = tid; i < 128; i += 512){ b2l[i] = Wx_b2[i]; w3l[i] = Wx_w3[i]; }
  __syncthreads();

  const int lane = tid & 63, w = tid >> 6;
  const int m = lane & 15, q = lane >> 4;
  unsigned short* S = Ssh[w];

  const int tiles = (E + 15) >> 4;
  const int wid = blockIdx.x * 8 + w;
  const int nwv = gridDim.x * 8;

  for (int tb = wid; tb < tiles; tb += nwv){
    const int e0 = tb << 4;

    int smy = 0, dmy = 0;
    float dxv = 0.f, dyv = 0.f, dzv = 0.f, rsv = 0.f;
    if (lane < 16){
      const int eC = min(e0 + lane, E - 1);
      smy = ss[eC]; dmy = ddv[eC];
      float4 d4 = daux[eC];
      dxv = d4.x; dyv = d4.y; dzv = d4.z;
      rsv = 2.5f * rcpf(sqrtf(d4.w + 1e-8f) + 1.0f);
    }
    const int s_m = __shfl(smy, m), d_m = __shfl(dmy, m);
    const float dxm = __shfl(dxv, m), dym = __shfl(dyv, m);
    const float dzm = __shfl(dzv, m), rsm = __shfl(rsv, m);

    // tail B-frag (ea only, k<16)
    union { short8 v; unsigned int u[4]; } at;
    at.u[0] = at.u[1] = at.u[2] = at.u[3] = 0u;
    if (q < 2)
      at.v = *(const short8*)(eaS + (size_t)min(e0 + m, E - 1) * 16 + q * 8);

    const unsigned short* pS = Axs + (size_t)s_m * HD + q * 4;
    const unsigned short* pD = Axd + (size_t)d_m * HD + q * 4;

    #pragma unroll
    for (int ph = 0; ph < 2; ++ph){
      uint2 gs[4], gd[4];
      #pragma unroll
      for (int j = 0; j < 4; ++j){
        gs[j] = *(const uint2*)(pS + (ph * 4 + j) * 16);
        gd[j] = *(const uint2*)(pD + (ph * 4 + j) * 16);
      }
      #pragma unroll
      for (int j = 0; j < 4; ++j){
        const int t = ph * 4 + j;
        float4v ci;
        ci[0] = unplo(gs[j].x) + unplo(gd[j].x);
        ci[1] = unphi(gs[j].x) + unphi(gd[j].x);
        ci[2] = unplo(gs[j].y) + unplo(gd[j].y);
        ci[3] = unphi(gs[j].y) + unphi(gd[j].y);
        short8 aB;
        if (q < 2) aB = *(const short8*)(Btl + (t * 16 + m) * 16 + q * 8);
        else { union { short8 v; unsigned int u[4]; } z; z.u[0]=z.u[1]=z.u[2]=z.u[3]=0u; aB = z.v; }
        float4v o = __builtin_amdgcn_mfma_f32_16x16x32_bf16(aB, at.v, ci, 0, 0, 0);
        uint2 ov;
        ov.x = packtrunc(siluf(o[0]), siluf(o[1]));
        ov.y = packtrunc(siluf(o[2]), siluf(o[3]));
        *(uint2*)(S + m * 140 + t * 16 + q * 4) = ov;
      }
    }

    float4v c2[8];
    #pragma unroll
    for (int t = 0; t < 8; ++t) c2[t] = (float4v){0.f, 0.f, 0.f, 0.f};
    #pragma unroll
    for (int step = 0; step < 4; ++step){
      short8 bU = *(const short8*)(S + m * 140 + step * 32 + q * 8);
      #pragma unroll
      for (int t = 0; t < 8; ++t){
        short8 aW = *(const short8*)(W2t + (size_t)(t * 16 + m) * 136 + step * 32 + q * 8);
        c2[t] = __builtin_amdgcn_mfma_f32_16x16x32_bf16(aW, bU, c2[t], 0, 0, 0);
      }
    }

    // coord weight: lane holds edge m; 1 tanh/lane via exp+rcp
    float p = 0.f;
    #pragma unroll
    for (int t = 0; t < 8; ++t){
      float4 bv = *(const float4*)(b2l + t * 16 + q * 4);
      float4 wv = *(const float4*)(w3l + t * 16 + q * 4);
      p = fmaf(siluf(c2[t][0] + bv.x), wv.x, p);
      p = fmaf(siluf(c2[t][1] + bv.y), wv.y, p);
      p = fmaf(siluf(c2[t][2] + bv.z), wv.z, p);
      p = fmaf(siluf(c2[t][3] + bv.w), wv.w, p);
    }
    p += __shfl_xor(p, 16); p += __shfl_xor(p, 32);
    const float th = 1.f - 2.f * rcpf(1.f + __expf(2.f * p));  // tanh(p)
    const float sc = th * rsm;
    const float comp = (q == 0) ? dxm : (q == 1) ? dym : dzm;
    const float contrib = comp * sc;   // meaningful for q<3

    // segmented emit: lanes 0..2 emit; contributions pulled via shfl
    __builtin_amdgcn_sched_barrier(0);
    int dp = __shfl(dmy, 0); float acc = 0.f;
    #pragma unroll
    for (int eg = 0; eg < 16; ++eg){
      int dc = __shfl(dmy, eg);
      float c = __shfl(contrib, ((lane & 3) << 4) + eg);
      if (dc != dp){                               // wave-uniform
        if (lane < 3) atomAddF(xout + (size_t)dp * 3 + lane, acc);
        acc = 0.f; dp = dc;
      }
      if (e0 + eg < E) acc += c;
    }
    if (lane < 3) atomAddF(xout + (size_t)dp * 3 + lane, acc);
  }
}

// ---------------------------------------------------------------------------
// Kernel 4: z2 = bf16( silu( zpre + msg @ Wh_w1[128:256] ) ). v7: 512 threads,
// 128-node tiles -> LDS 69.6KB, 2 blocks/CU = 16 waves/CU (4/SIMD, was 3).
// ---------------------------------------------------------------------------
__global__ void __launch_bounds__(512) k_h1b2(
    const unsigned short* __restrict__ msg, const unsigned short* __restrict__ zpre,
    const float* __restrict__ Wh_w1, unsigned short* __restrict__ z2, int N)
{
  __shared__ unsigned short Wt[128 * 136];     // 34816 B
  __shared__ unsigned short OutS[128 * 136];   // 34816 B -> total 69632 B

  for (int i = threadIdx.x; i < 128 * 128; i += 512){
    int k = i >> 7, col = i & 127;
    Wt[col * 136 + k] = f2b(Wh_w1[(128 + k) * 128 + col]);
  }
  __syncthreads();

  const int lane = threadIdx.x & 63, w = threadIdx.x >> 6;   // w = 0..7
  const int m = lane & 15, q = lane >> 4;

  const int ntiles = (N + 127) >> 7;
  for (int tile = blockIdx.x; tile < ntiles; tile += gridDim.x){
    const int n0 = tile << 7;
    const int n = min(n0 + w * 16 + m, N - 1);

    short8 a[4];
    #pragma unroll
    for (int step = 0; step < 4; ++step)
      a[step] = *(const short8*)(msg + (size_t)n * 128 + step * 32 + q * 8);

    float4v acc[8];
    #pragma unroll
    for (int t = 0; t < 8; ++t) acc[t] = (float4v){0.f, 0.f, 0.f, 0.f};
    #pragma unroll
    for (int step = 0; step < 4; ++step){
      #pragma unroll
      for (int t = 0; t < 8; ++t){
        short8 b = *(const short8*)(Wt + (size_t)(t * 16 + m) * 136 + step * 32 + q * 8);
        acc[t] = __builtin_amdgcn_mfma_f32_16x16x32_bf16(a[step], b, acc[t], 0, 0, 0);
      }
    }

    #pragma unroll
    for (int t = 0; t < 8; ++t)
      #pragma unroll
      for (int r = 0; r < 4; ++r)
        OutS[(w * 16 + q * 4 + r) * 136 + t * 16 + m] = f2b(acc[t][r]);
    __syncthreads();
    for (int i = threadIdx.x; i < 128 * 16; i += 512){
      int node = i >> 4, seg = i & 15;
      int nn = n0 + node;
      if (nn < N){
        uint4 dv = *(const uint4*)(OutS + node * 136 + seg * 8);
        uint4 zv = *(const uint4*)(zpre + (size_t)nn * 128 + seg * 8);
        float fd[8], fz[8];
        unp8(dv, fd); unp8(zv, fz);
        uint4 ov;
        ov.x = packbf(siluf(fz[0] + fd[0]), siluf(fz[1] + fd[1]));
        ov.y = packbf(siluf(fz[2] + fd[2]), siluf(fz[3] + fd[3]));
        ov.z = packbf(siluf(fz[4] + fd[4]), siluf(fz[5] + fd[5]));
        ov.w = packbf(siluf(fz[6] + fd[6]), siluf(fz[7] + fd[7]));
        *(uint4*)(z2 + (size_t)nn * 128 + seg * 8) = ov;
      }
    }
    __syncthreads();
  }
}

// ---------------------------------------------------------------------------
// Kernel 5: hout = h + z2 @ Wh_w2 + Wh_b2. v7: NO output staging — read h and
// write hout directly from the accumulator layout (64B segments, L2-absorbed).
// LDS = Wt only (34.8KB) -> 4 blocks/CU = 16 waves/CU (4/SIMD, was 2).
// ---------------------------------------------------------------------------
__global__ void __launch_bounds__(256) k_h22(
    const float* __restrict__ h, const unsigned short* __restrict__ z2,
    const float* __restrict__ Wh_w2, const float* __restrict__ Wh_b2,
    float* __restrict__ hout, int N)
{
  __shared__ unsigned short Wt[128 * 136];     // 34816 B only

  for (int i = threadIdx.x; i < 128 * 128; i += 256){
    int k = i >> 7, col = i & 127;
    Wt[col * 136 + k] = f2b(Wh_w2[k * 128 + col]);
  }
  __syncthreads();

  const int lane = threadIdx.x & 63, w = threadIdx.x >> 6;
  const int m = lane & 15, q = lane >> 4;
  float bb[8];
  #pragma unroll
  for (int t = 0; t < 8; ++t) bb[t] = Wh_b2[t * 16 + m];

  const int ntiles = (N + 63) >> 6;
  for (int tile = blockIdx.x; tile < ntiles; tile += gridDim.x){
    const int n0 = tile << 6;
    const int n = min(n0 + w * 16 + m, N - 1);

    short8 a[4];
    #pragma unroll
    for (int step = 0; step < 4; ++step)
      a[step] = *(const short8*)(z2 + (size_t)n * 128 + step * 32 + q * 8);

    float4v acc[8];
    #pragma unroll
    for (int t = 0; t < 8; ++t) acc[t] = (float4v){0.f, 0.f, 0.f, 0.f};
    #pragma unroll
    for (int step = 0; step < 4; ++step){
      #pragma unroll
      for (int t = 0; t < 8; ++t){
        short8 b = *(const short8*)(Wt + (size_t)(t * 16 + m) * 136 + step * 32 + q * 8);
        acc[t] = __builtin_amdgcn_mfma_f32_16x16x32_bf16(a[step], b, acc[t], 0, 0, 0);
      }
    }

    // direct epilogue: lane (m,q) owns nodes n0 + w*16 + q*4 + r, feature t*16+m
    #pragma unroll
    for (int r = 0; r < 4; ++r){
      const int nn = n0 + w * 16 + q * 4 + r;
      if (nn < N){
        const size_t base = (size_t)nn * 128 + m;
        #pragma unroll
        for (int t = 0; t < 8; ++t)
          hout[base + t * 16] = h[base + t * 16] + acc[t][r] + bb[t];
      }
    }
  }
}

extern "C" void kernel_launch(void* const* d_in, const int* in_sizes, int n_in,
                              void* d_out, int out_size, void* d_ws, size_t ws_size,
                              hipStream_t stream)
{
  const float* h      = (const float*)d_in[0];
  const float* x      = (const float*)d_in[1];
  const int*   ei     = (const int*)  d_in[2];
  const float* ea     = (const float*)d_in[3];
  const float* t_emb  = (const float*)d_in[4];
  const float* We_w1  = (const float*)d_in[5];
  const float* We_b1  = (const float*)d_in[6];
  const float* We_w2  = (const float*)d_in[7];
  const float* We_b2  = (const float*)d_in[8];
  const float* Watt_w = (const float*)d_in[9];
  const float* Watt_b = (const float*)d_in[10];
  const float* Wx_w1  = (const float*)d_in[11];
  const float* Wx_b1  = (const float*)d_in[12];
  const float* Wx_w2  = (const float*)d_in[13];
  const float* Wx_b2  = (const float*)d_in[14];
  const float* Wx_w3  = (const float*)d_in[15];
  const float* Wh_w1  = (const float*)d_in[16];
  const float* Wh_b1  = (const float*)d_in[17];
  const float* Wh_w2  = (const float*)d_in[18];
  const float* Wh_b2  = (const float*)d_in[19];

  const int N = in_sizes[0] / HD;
  const int E = in_sizes[2] / 2;

  char* ws = (char*)d_ws;
  unsigned short* Aes  = (unsigned short*)ws;  ws += (size_t)N * HD * 2;
  unsigned short* Aed  = (unsigned short*)ws;  ws += (size_t)N * HD * 2;
  unsigned short* Axs  = (unsigned short*)ws;  ws += (size_t)N * HD * 2;
  unsigned short* Axd  = (unsigned short*)ws;  ws += (size_t)N * HD * 2;
  unsigned short* zpre = (unsigned short*)ws;  ws += (size_t)N * HD * 2;
  unsigned short* z2   = (unsigned short*)ws;  ws += (size_t)N * HD * 2;
  unsigned short* msg_agg = (unsigned short*)ws; ws += (size_t)N * HD * 2;
  unsigned short* hb   = (unsigned short*)ws;  ws += (size_t)N * HD * 2;
  unsigned short* tb   = (unsigned short*)ws;  ws += (size_t)N * TD * 2;

  // Overlays into [hb .. hb+16MB) AFTER k_pre2 consumed hb/tb:
  //   ss (E ints) | ddv (E ints) | daux (E float4) = 24E = 14.4MB <= 16MB
  char* sortbase = (char*)hb;
  int*    ss_   = (int*)sortbase;
  int*    ddv_  = ss_ + E;
  float4* daux_ = (float4*)(sortbase + (size_t)8 * E);
  // cnt/off live in msg_agg's first 2N ints during sort (re-zeroed after)
  int* cnt_ = (int*)msg_agg;
  int* off_ = cnt_ + N;

  float* hout = (float*)d_out;
  float* xout = hout + (size_t)N * HD;
  // eaS (E x 16 bf16, sorted order) borrows hout space; k_h22 (last kernel)
  // fully overwrites hout afterwards. Stream order guarantees safety.
  unsigned short* eaS_ = (unsigned short*)hout;

  hipMemsetAsync(msg_agg, 0, (size_t)N * HD * 2, stream);   // also zeroes cnt/off
  hipMemcpyAsync(xout, x, (size_t)N * 3 * 4, hipMemcpyDeviceToDevice, stream);

  k_cvt<<<400, 256, 0, stream>>>(h, hb, N * (HD / 8));
  k_cvt<<<100, 256, 0, stream>>>(t_emb, tb, N * (TD / 8));

  dim3 gP(96, 5);
  k_pre2<<<gP, 512, 0, stream>>>(hb, tb, We_w1, We_b1, Wx_w1, Wx_b1,
                                 Wh_w1, Wh_b1, Aes, Aed, Axs, Axd, zpre, N);

  // counting sort by dst + per-edge precompute (hb/tb free after k_pre2)
  k_hist<<<512, 256, 0, stream>>>(ei, cnt_, E);
  k_scan<<<1, 1024, 0, stream>>>(cnt_, off_, N);
  k_scatter<<<1024, 256, 0, stream>>>(ei, x, ea, off_, ss_, ddv_, daux_, eaS_, E);

  // re-zero the msg_agg area that hosted cnt/off
  hipMemsetAsync(msg_agg, 0, (size_t)2 * N * sizeof(int), stream);

  k_edge_msg<<<512, 512, 0, stream>>>(ss_, ddv_, eaS_, daux_, Aes, Aed,
                                      We_w1, We_w2, We_b2, Watt_w, Watt_b,
                                      msg_agg, E);
  k_edge_coord<<<512, 512, 0, stream>>>(ss_, ddv_, eaS_, daux_, Axs, Axd,
                                        Wx_w1, Wx_w2, Wx_b2, Wx_w3, xout, E);
  k_h1b2<<<256, 512, 0, stream>>>(msg_agg, zpre, Wh_w1, z2, N);
  k_h22<<<768, 256, 0, stream>>>(h, z2, Wh_w2, Wh_b2, hout, N);
}

// Round 9
// 513.650 us; speedup vs baseline: 2.8817x; 1.0094x over previous
//
#include <hip/hip_runtime.h>
#include <hip/hip_bf16.h>

#define HD 128
#define ED 16
#define TD 32

typedef __attribute__((ext_vector_type(8))) short short8;
typedef __attribute__((ext_vector_type(4))) float float4v;

__device__ __forceinline__ float rcpf(float x){ return __builtin_amdgcn_rcpf(x); }
__device__ __forceinline__ float siluf(float v){ return v * rcpf(1.0f + __expf(-v)); }

// bf16 pack/unpack helpers
__device__ __forceinline__ unsigned int bfbits(float x){          // RTNE
  unsigned int a = __float_as_uint(x);
  return (a + 0x7fffu + ((a >> 16) & 1u)) >> 16;
}
__device__ __forceinline__ unsigned int packbf(float lo, float hi){  // RTNE pair
  return (bfbits(lo) & 0xffffu) | (bfbits(hi) << 16);
}
// 1-op truncation pack via v_perm_b32: [lo.b2, lo.b3, hi.b2, hi.b3]
__device__ __forceinline__ unsigned int packtrunc(float lo, float hi){
  return __builtin_amdgcn_perm(__float_as_uint(hi), __float_as_uint(lo), 0x07060302u);
}
__device__ __forceinline__ float unplo(unsigned int w){ return __uint_as_float(w << 16); }
__device__ __forceinline__ float unphi(unsigned int w){ return __uint_as_float(w & 0xffff0000u); }
__device__ __forceinline__ unsigned short f2b(float x){ return (unsigned short)bfbits(x); }

__device__ __forceinline__ void unp8(uint4 u, float* f){
  f[0]=unplo(u.x); f[1]=unphi(u.x); f[2]=unplo(u.y); f[3]=unphi(u.y);
  f[4]=unplo(u.z); f[5]=unphi(u.z); f[6]=unplo(u.w); f[7]=unphi(u.w);
}

__device__ __forceinline__ void atomAddF(float* p, float v){
  unsafeAtomicAdd(p, v);  // HW global_atomic_add_f32 on gfx950
}

// packed bf16 atomic add: one instruction adds 2 bf16 lanes-worth
__device__ __forceinline__ void atomAddBF2(unsigned short* p, unsigned int packed){
  asm volatile("global_atomic_pk_add_bf16 %0, %1, off"
               :: "v"((unsigned long long)(uintptr_t)p), "v"(packed) : "memory");
}

// ---------------------------------------------------------------------------
// Kernel 0 (v9): fused prep — h->bf16, t_emb->bf16, dst histogram.
// Merges 3 dispatches into 1.
// ---------------------------------------------------------------------------
__global__ void __launch_bounds__(256) k_prep(
    const float* __restrict__ h, const float* __restrict__ t_emb,
    const int* __restrict__ ei,
    unsigned short* __restrict__ hb, unsigned short* __restrict__ tbuf,
    int* __restrict__ cnt, int nh8, int nt8, int E)
{
  const int i0 = blockIdx.x * 256 + threadIdx.x, st = gridDim.x * 256;
  for (int i = i0; i < nh8; i += st){
    float4 v0 = *(const float4*)(h + (size_t)i * 8);
    float4 v1 = *(const float4*)(h + (size_t)i * 8 + 4);
    uint4 o;
    o.x = packbf(v0.x, v0.y); o.y = packbf(v0.z, v0.w);
    o.z = packbf(v1.x, v1.y); o.w = packbf(v1.z, v1.w);
    *(uint4*)(hb + (size_t)i * 8) = o;
  }
  for (int i = i0; i < nt8; i += st){
    float4 v0 = *(const float4*)(t_emb + (size_t)i * 8);
    float4 v1 = *(const float4*)(t_emb + (size_t)i * 8 + 4);
    uint4 o;
    o.x = packbf(v0.x, v0.y); o.y = packbf(v0.z, v0.w);
    o.z = packbf(v1.x, v1.y); o.w = packbf(v1.z, v1.w);
    *(uint4*)(tbuf + (size_t)i * 8) = o;
  }
  for (int e = i0; e < E; e += st)
    atomicAdd(&cnt[ei[E + e]], 1);
}

__global__ void __launch_bounds__(1024) k_scan(
    const int* __restrict__ cnt, int* __restrict__ off, int n)
{
  const int tid = threadIdx.x, lane = tid & 63, wv = tid >> 6;  // 16 waves
  __shared__ int wsum[16];
  __shared__ int carryS;
  if (tid == 0) carryS = 0;
  __syncthreads();
  const int CH = 1024 * 8;
  for (int base = 0; base < n; base += CH){
    const int idx0 = base + tid * 8;
    int v[8];
    #pragma unroll
    for (int j = 0; j < 8; ++j){ int i = idx0 + j; v[j] = (i < n) ? cnt[i] : 0; }
    #pragma unroll
    for (int j = 1; j < 8; ++j) v[j] += v[j - 1];   // local inclusive
    const int tot = v[7];
    int sc = tot;                                    // wave inclusive scan
    #pragma unroll
    for (int d = 1; d < 64; d <<= 1){ int t = __shfl_up(sc, d); if (lane >= d) sc += t; }
    if (lane == 63) wsum[wv] = sc;
    __syncthreads();
    if (tid < 16){
      int s = wsum[tid];
      #pragma unroll
      for (int d = 1; d < 16; d <<= 1){ int t = __shfl_up(s, d); if (tid >= d) s += t; }
      wsum[tid] = s;
    }
    __syncthreads();
    const int base_excl = carryS + (wv > 0 ? wsum[wv - 1] : 0) + (sc - tot);
    #pragma unroll
    for (int j = 0; j < 8; ++j){
      int i = idx0 + j;
      if (i < n) off[i] = base_excl + (j > 0 ? v[j - 1] : 0);
    }
    __syncthreads();
    if (tid == 0) carryS += wsum[15];
    __syncthreads();
  }
}

__global__ void __launch_bounds__(256) k_scatter(
    const int* __restrict__ ei, const float* __restrict__ x,
    const float* __restrict__ ea, int* __restrict__ off,
    int* __restrict__ ss, int* __restrict__ ddv,
    float4* __restrict__ daux, unsigned short* __restrict__ eaS, int E)
{
  for (int e = blockIdx.x * 256 + threadIdx.x; e < E; e += gridDim.x * 256){
    int s = ei[e], d = ei[E + e];
    int pos = atomicAdd(&off[d], 1);
    ss[pos] = s; ddv[pos] = d;
    float dx = x[s * 3 + 0] - x[d * 3 + 0];
    float dy = x[s * 3 + 1] - x[d * 3 + 1];
    float dz = x[s * 3 + 2] - x[d * 3 + 2];
    float4 da; da.x = dx; da.y = dy; da.z = dz; da.w = dx*dx + dy*dy + dz*dz;
    daux[pos] = da;
    const float4* e4 = (const float4*)(ea + (size_t)e * ED);
    float4 a = e4[0], b = e4[1], c = e4[2], dd = e4[3];
    uint4 o1, o2;
    o1.x = packtrunc(a.x, a.y); o1.y = packtrunc(a.z, a.w);
    o1.z = packtrunc(b.x, b.y); o1.w = packtrunc(b.z, b.w);
    o2.x = packtrunc(c.x, c.y); o2.y = packtrunc(c.z, c.w);
    o2.z = packtrunc(dd.x, dd.y); o2.w = packtrunc(dd.z, dd.w);
    *(uint4*)(eaS + (size_t)pos * 16) = o1;
    *(uint4*)(eaS + (size_t)pos * 16 + 8) = o2;
  }
}

// ---------------------------------------------------------------------------
// Kernel 1: node-side first-layer GEMMs via MFMA (r8 structure, frozen).
// ---------------------------------------------------------------------------
__global__ void __launch_bounds__(512) k_pre2(
    const unsigned short* __restrict__ hb, const unsigned short* __restrict__ tb,
    const float* __restrict__ We_w1, const float* __restrict__ We_b1,
    const float* __restrict__ Wx_w1, const float* __restrict__ Wx_b1,
    const float* __restrict__ Wh_w1, const float* __restrict__ Wh_b1,
    unsigned short* __restrict__ Aes, unsigned short* __restrict__ Aed,
    unsigned short* __restrict__ Axs, unsigned short* __restrict__ Axd,
    unsigned short* __restrict__ zpre, int N)
{
  __shared__ unsigned short Wt[128 * 168];     // 43008 B
  __shared__ unsigned short OutS[128 * 136];   // 34816 B -> total 77824 B

  const int group = blockIdx.y;
  const float* Wsrc = (group <= 1) ? We_w1 : (group <= 3) ? Wx_w1 : Wh_w1;
  const float* bias = (group == 0) ? We_b1 : (group == 2) ? Wx_b1
                    : (group == 4) ? Wh_b1 : nullptr;
  unsigned short* out = (group == 0) ? Aes : (group == 1) ? Aed
                      : (group == 2) ? Axs : (group == 3) ? Axd : zpre;
  const int rowBase = (group == 1 || group == 3) ? 128 : 0;
  const int tBase   = (group == 0) ? 273 : (group == 2) ? 272 : -1;

  for (int i = threadIdx.x; i < 160 * 128; i += 512){
    int k = i >> 7, col = i & 127;
    float wv = 0.f;
    if (k < 128)      wv = Wsrc[(rowBase + k) * 128 + col];
    else if (tBase >= 0) wv = Wsrc[(tBase + (k - 128)) * 128 + col];
    Wt[col * 168 + k] = f2b(wv);
  }
  __syncthreads();

  const int lane = threadIdx.x & 63, w = threadIdx.x >> 6;   // w = 0..7
  const int m = lane & 15, q = lane >> 4;
  float bb[8];
  #pragma unroll
  for (int t = 0; t < 8; ++t) bb[t] = bias ? bias[t * 16 + m] : 0.f;

  const int ntiles = (N + 127) >> 7;
  for (int tile = blockIdx.x; tile < ntiles; tile += gridDim.x){
    const int n0 = tile << 7;
    const int n = min(n0 + w * 16 + m, N - 1);

    short8 a[5];
    #pragma unroll
    for (int step = 0; step < 4; ++step)
      a[step] = *(const short8*)(hb + (size_t)n * 128 + step * 32 + q * 8);
    a[4] = *(const short8*)(tb + (size_t)n * 32 + q * 8);

    float4v acc[8];
    #pragma unroll
    for (int t = 0; t < 8; ++t) acc[t] = (float4v){0.f, 0.f, 0.f, 0.f};
    #pragma unroll
    for (int step = 0; step < 5; ++step){
      #pragma unroll
      for (int t = 0; t < 8; ++t){
        short8 b = *(const short8*)(Wt + (size_t)(t * 16 + m) * 168 + step * 32 + q * 8);
        acc[t] = __builtin_amdgcn_mfma_f32_16x16x32_bf16(a[step], b, acc[t], 0, 0, 0);
      }
    }

    #pragma unroll
    for (int t = 0; t < 8; ++t)
      #pragma unroll
      for (int r = 0; r < 4; ++r)
        OutS[(w * 16 + q * 4 + r) * 136 + t * 16 + m] = f2b(acc[t][r] + bb[t]);
    __syncthreads();
    for (int i = threadIdx.x; i < 128 * 16; i += 512){
      int node = i >> 4, seg = i & 15;
      int nn = n0 + node;
      if (nn < N)
        *(uint4*)(out + (size_t)nn * 128 + seg * 8) =
            *(const uint4*)(OutS + node * 136 + seg * 8);
    }
    __syncthreads();
  }
}

// ---------------------------------------------------------------------------
// Kernel 2: message path over dst-SORTED edges. v9:
//  - ALL 16 C-init gathers issued before any consume (deeper MLP);
//  - next tile's index/scalar loads prefetched before the MFMA phase
//    (current values extracted to s_m/d_m/dm via shfl first, then regs reused).
// ---------------------------------------------------------------------------
__global__ void __launch_bounds__(512, 4) k_edge_msg(
    const int* __restrict__ ss, const int* __restrict__ ddv,
    const unsigned short* __restrict__ eaS, const float4* __restrict__ daux,
    const unsigned short* __restrict__ Aes, const unsigned short* __restrict__ Aed,
    const float* __restrict__ We_w1, const float* __restrict__ We_w2,
    const float* __restrict__ We_b2, const float* __restrict__ Watt_w,
    const float* __restrict__ Watt_b,
    unsigned short* __restrict__ msg_agg, int E)
{
  __shared__ __align__(16) unsigned short W2t[128 * 136];   // 34816 B [col][k]
  __shared__ __align__(16) unsigned short Btl[128 * 24];    // 6144 B  [col][k<24]
  __shared__ __align__(16) unsigned short Ssh[8][16 * 140]; // 35840 B [edge][n]
  __shared__ __align__(16) float b2l[128];                  // 512 B
  __shared__ __align__(16) float wal[128];                  // 512 B
  // total 77824 B -> 2 blocks/CU (16 waves)

  const int tid = threadIdx.x;
  for (int i = tid; i < 128 * 128; i += 512){
    int col = i & 127, k = i >> 7;
    W2t[col * 136 + k] = f2b(We_w2[k * 128 + col]);
  }
  for (int i = tid; i < 128 * 24; i += 512){
    int col = i / 24, k = i % 24;
    float wv = (k < 16) ? We_w1[(257 + k) * 128 + col]
             : (k == 16 ? We_w1[256 * 128 + col] : 0.f);
    Btl[col * 24 + k] = f2b(wv);
  }
  for (int i = tid; i < 128; i += 512){ b2l[i] = We_b2[i]; wal[i] = Watt_w[i]; }
  __syncthreads();

  const int lane = tid & 63, w = tid >> 6;
  const int m = lane & 15, q = lane >> 4;
  const float attb = Watt_b[0];
  unsigned short* S = Ssh[w];

  const int tiles = (E + 15) >> 4;
  const int wid = blockIdx.x * 8 + w;
  const int nwv = gridDim.x * 8;

  // index/scalar state for the CURRENT tile (lanes 0..15)
  int smy = 0, dmy = 0; float dval = 0.f;
  if (lane < 16){
    const int eC = min((wid << 4) + lane, E - 1);
    smy = ss[eC]; dmy = ddv[eC]; dval = daux[eC].w;
  }

  for (int tb = wid; tb < tiles; tb += nwv){
    const int e0 = tb << 4;

    // extract current tile's per-edge values (then regs are free for prefetch)
    const int s_m = __shfl(smy, m), d_m = __shfl(dmy, m);
    const float dm = __shfl(dval, m);
    const int dmyCur = dmy;                     // preserved for the emit phase

    // tail B-frag: lane = edge m, k-slice q*8; k<16 = ea, k==16 = dist
    union { short8 v; unsigned int u[4]; } at;
    at.u[0] = at.u[1] = at.u[2] = at.u[3] = 0u;
    if (q < 2){
      at.v = *(const short8*)(eaS + (size_t)min(e0 + m, E - 1) * 16 + q * 8);
    } else if (q == 2){
      at.u[0] = __float_as_uint(dm) >> 16;
    }

    // issue ALL 16 C-init gathers up front (deep MLP)
    const unsigned short* pS = Aes + (size_t)s_m * HD + q * 4;
    const unsigned short* pD = Aed + (size_t)d_m * HD + q * 4;
    uint2 gs[8], gd[8];
    #pragma unroll
    for (int j = 0; j < 8; ++j){
      gs[j] = *(const uint2*)(pS + j * 16);
      gd[j] = *(const uint2*)(pD + j * 16);
    }

    // prefetch NEXT tile's index/scalar loads (overwrites smy/dmy/dval)
    {
      const int en = min(tb + nwv, tiles - 1) << 4;
      if (lane < 16){
        const int eC = min(en + lane, E - 1);
        smy = ss[eC]; dmy = ddv[eC]; dval = daux[eC].w;
      }
    }

    // tail MFMA swapped; C = f32 sum of gathers; silu -> S
    #pragma unroll
    for (int t = 0; t < 8; ++t){
      float4v ci;
      ci[0] = unplo(gs[t].x) + unplo(gd[t].x);
      ci[1] = unphi(gs[t].x) + unphi(gd[t].x);
      ci[2] = unplo(gs[t].y) + unplo(gd[t].y);
      ci[3] = unphi(gs[t].y) + unphi(gd[t].y);
      short8 aB;
      if (q < 3) aB = *(const short8*)(Btl + (t * 16 + m) * 24 + q * 8);
      else { union { short8 v; unsigned int u[4]; } z; z.u[0]=z.u[1]=z.u[2]=z.u[3]=0u; aB = z.v; }
      float4v o = __builtin_amdgcn_mfma_f32_16x16x32_bf16(aB, at.v, ci, 0, 0, 0);
      uint2 ov;
      ov.x = packtrunc(siluf(o[0]), siluf(o[1]));
      ov.y = packtrunc(siluf(o[2]), siluf(o[3]));
      *(uint2*)(S + m * 140 + t * 16 + q * 4) = ov;
    }

    // layer-2 MFMA swapped: A = W2^T from LDS, B = u^T from S
    float4v c2[8];
    #pragma unroll
    for (int t = 0; t < 8; ++t) c2[t] = (float4v){0.f, 0.f, 0.f, 0.f};
    #pragma unroll
    for (int step = 0; step < 4; ++step){
      short8 bU = *(const short8*)(S + m * 140 + step * 32 + q * 8);
      #pragma unroll
      for (int t = 0; t < 8; ++t){
        short8 aW = *(const short8*)(W2t + (size_t)(t * 16 + m) * 136 + step * 32 + q * 8);
        c2[t] = __builtin_amdgcn_mfma_f32_16x16x32_bf16(aW, bU, c2[t], 0, 0, 0);
      }
    }

    // attention: lane holds edge m's n-values; 1 sigmoid/lane, 2-shfl reduce
    float p = 0.f;
    #pragma unroll
    for (int t = 0; t < 8; ++t){
      float4 bv = *(const float4*)(b2l + t * 16 + q * 4);
      float4 wv = *(const float4*)(wal + t * 16 + q * 4);
      c2[t][0] += bv.x; c2[t][1] += bv.y; c2[t][2] += bv.z; c2[t][3] += bv.w;
      p = fmaf(c2[t][0], wv.x, p); p = fmaf(c2[t][1], wv.y, p);
      p = fmaf(c2[t][2], wv.z, p); p = fmaf(c2[t][3], wv.w, p);
    }
    p += __shfl_xor(p, 16); p += __shfl_xor(p, 32);
    const float att = rcpf(1.f + __expf(-(p + attb)));
    #pragma unroll
    for (int t = 0; t < 8; ++t){
      uint2 ov;
      ov.x = packtrunc(att * c2[t][0], att * c2[t][1]);
      ov.y = packtrunc(att * c2[t][2], att * c2[t][3]);
      *(uint2*)(S + m * 140 + t * 16 + q * 4) = ov;
    }

    // segmented f32 reduction over sorted dsts; one pk atomic per run
    __builtin_amdgcn_sched_barrier(0);
    float a0 = 0.f, a1 = 0.f;
    int dp = __shfl(dmyCur, 0);
    #pragma unroll
    for (int half = 0; half < 2; ++half){
      unsigned int vv[8]; int dvr[8];
      #pragma unroll
      for (int j = 0; j < 8; ++j){
        const int eg = half * 8 + j;
        vv[j]  = *(const unsigned int*)(S + eg * 140 + lane * 2);
        dvr[j] = __shfl(dmyCur, eg);
      }
      #pragma unroll
      for (int j = 0; j < 8; ++j){
        if (dvr[j] != dp){                      // wave-uniform branch
          atomAddBF2(msg_agg + (size_t)dp * HD + lane * 2, packbf(a0, a1));
          a0 = a1 = 0.f; dp = dvr[j];
        }
        if (e0 + half * 8 + j < E){ a0 += unplo(vv[j]); a1 += unphi(vv[j]); }
      }
    }
    atomAddBF2(msg_agg + (size_t)dp * HD + lane * 2, packbf(a0, a1));
  }
}

// ---------------------------------------------------------------------------
// Kernel 3: coord path over dst-SORTED edges. Same v9 treatment.
// ---------------------------------------------------------------------------
__global__ void __launch_bounds__(512, 4) k_edge_coord(
    const int* __restrict__ ss, const int* __restrict__ ddv,
    const unsigned short* __restrict__ eaS, const float4* __restrict__ daux,
    const unsigned short* __restrict__ Axs, const unsigned short* __restrict__ Axd,
    const float* __restrict__ Wx_w1, const float* __restrict__ Wx_w2,
    const float* __restrict__ Wx_b2, const float* __restrict__ Wx_w3,
    float* __restrict__ xout, int E)
{
  __shared__ __align__(16) unsigned short W2t[128 * 136];   // 34816 B
  __shared__ __align__(16) unsigned short Btl[128 * 16];    // 4096 B [col][k<16]
  __shared__ __align__(16) unsigned short Ssh[8][16 * 140]; // 35840 B
  __shared__ __align__(16) float b2l[128];                  // 512 B
  __shared__ __align__(16) float w3l[128];                  // 512 B
  // total 75776 B -> 2 blocks/CU

  const int tid = threadIdx.x;
  for (int i = tid; i < 128 * 128; i += 512){
    int col = i & 127, k = i >> 7;
    W2t[col * 136 + k] = f2b(Wx_w2[k * 128 + col]);
  }
  for (int i = tid; i < 128 * 16; i += 512){
    int col = i >> 4, k = i & 15;
    Btl[col * 16 + k] = f2b(Wx_w1[(256 + k) * 128 + col]);
  }
  for (int i = tid; i < 128; i += 512){ b2l[i] = Wx_b2[i]; w3l[i] = Wx_w3[i]; }
  __syncthreads();

  const int lane = tid & 63, w = tid >> 6;
  const int m = lane & 15, q = lane >> 4;
  unsigned short* S = Ssh[w];

  const int tiles = (E + 15) >> 4;
  const int wid = blockIdx.x * 8 + w;
  const int nwv = gridDim.x * 8;

  // index/scalar state for CURRENT tile (lanes 0..15); d4 kept raw
  int smy = 0, dmy = 0;
  float4 d4 = {0.f, 0.f, 0.f, 0.f};
  if (lane < 16){
    const int eC = min((wid << 4) + lane, E - 1);
    smy = ss[eC]; dmy = ddv[eC]; d4 = daux[eC];
  }

  for (int tb = wid; tb < tiles; tb += nwv){
    const int e0 = tb << 4;

    // extract current tile's values via shfl (lanes>=16 hold garbage d4; only
    // lanes m<16 are sourced)
    const float rsv = 2.5f * rcpf(sqrtf(d4.w + 1e-8f) + 1.0f);
    const int s_m = __shfl(smy, m), d_m = __shfl(dmy, m);
    const float dxm = __shfl(d4.x, m), dym = __shfl(d4.y, m);
    const float dzm = __shfl(d4.z, m), rsm = __shfl(rsv, m);
    const int dmyCur = dmy;

    // tail B-frag (ea only, k<16)
    union { short8 v; unsigned int u[4]; } at;
    at.u[0] = at.u[1] = at.u[2] = at.u[3] = 0u;
    if (q < 2)
      at.v = *(const short8*)(eaS + (size_t)min(e0 + m, E - 1) * 16 + q * 8);

    // issue ALL 16 C-init gathers up front
    const unsigned short* pS = Axs + (size_t)s_m * HD + q * 4;
    const unsigned short* pD = Axd + (size_t)d_m * HD + q * 4;
    uint2 gs[8], gd[8];
    #pragma unroll
    for (int j = 0; j < 8; ++j){
      gs[j] = *(const uint2*)(pS + j * 16);
      gd[j] = *(const uint2*)(pD + j * 16);
    }

    // prefetch NEXT tile's index/scalar loads
    {
      const int en = min(tb + nwv, tiles - 1) << 4;
      if (lane < 16){
        const int eC = min(en + lane, E - 1);
        smy = ss[eC]; dmy = ddv[eC]; d4 = daux[eC];
      }
    }

    #pragma unroll
    for (int t = 0; t < 8; ++t){
      float4v ci;
      ci[0] = unplo(gs[t].x) + unplo(gd[t].x);
      ci[1] = unphi(gs[t].x) + unphi(gd[t].x);
      ci[2] = unplo(gs[t].y) + unplo(gd[t].y);
      ci[3] = unphi(gs[t].y) + unphi(gd[t].y);
      short8 aB;
      if (q < 2) aB = *(const short8*)(Btl + (t * 16 + m) * 16 + q * 8);
      else { union { short8 v; unsigned int u[4]; } z; z.u[0]=z.u[1]=z.u[2]=z.u[3]=0u; aB = z.v; }
      float4v o = __builtin_amdgcn_mfma_f32_16x16x32_bf16(aB, at.v, ci, 0, 0, 0);
      uint2 ov;
      ov.x = packtrunc(siluf(o[0]), siluf(o[1]));
      ov.y = packtrunc(siluf(o[2]), siluf(o[3]));
      *(uint2*)(S + m * 140 + t * 16 + q * 4) = ov;
    }

    float4v c2[8];
    #pragma unroll
    for (int t = 0; t < 8; ++t) c2[t] = (float4v){0.f, 0.f, 0.f, 0.f};
    #pragma unroll
    for (int step = 0; step < 4; ++step){
      short8 bU = *(const short8*)(S + m * 140 + step * 32 + q * 8);
      #pragma unroll
      for (int t = 0; t < 8; ++t){
        short8 aW = *(const short8*)(W2t + (size_t)(t * 16 + m) * 136 + step * 32 + q * 8);
        c2[t] = __builtin_amdgcn_mfma_f32_16x16x32_bf16(aW, bU, c2[t], 0, 0, 0);
      }
    }

    // coord weight: lane holds edge m; 1 tanh/lane via exp+rcp
    float p = 0.f;
    #pragma unroll
    for (int t = 0; t < 8; ++t){
      float4 bv = *(const float4*)(b2l + t * 16 + q * 4);
      float4 wv = *(const float4*)(w3l + t * 16 + q * 4);
      p = fmaf(siluf(c2[t][0] + bv.x), wv.x, p);
      p = fmaf(siluf(c2[t][1] + bv.y), wv.y, p);
      p = fmaf(siluf(c2[t][2] + bv.z), wv.z, p);
      p = fmaf(siluf(c2[t][3] + bv.w), wv.w, p);
    }
    p += __shfl_xor(p, 16); p += __shfl_xor(p, 32);
    const float th = 1.f - 2.f * rcpf(1.f + __expf(2.f * p));  // tanh(p)
    const float sc = th * rsm;
    const float comp = (q == 0) ? dxm : (q == 1) ? dym : dzm;
    const float contrib = comp * sc;   // meaningful for q<3

    // segmented emit: lanes 0..2 emit; contributions pulled via shfl
    __builtin_amdgcn_sched_barrier(0);
    int dp = __shfl(dmyCur, 0); float acc = 0.f;
    #pragma unroll
    for (int eg = 0; eg < 16; ++eg){
      int dc = __shfl(dmyCur, eg);
      float c = __shfl(contrib, ((lane & 3) << 4) + eg);
      if (dc != dp){                               // wave-uniform
        if (lane < 3) atomAddF(xout + (size_t)dp * 3 + lane, acc);
        acc = 0.f; dp = dc;
      }
      if (e0 + eg < E) acc += c;
    }
    if (lane < 3) atomAddF(xout + (size_t)dp * 3 + lane, acc);
  }
}

// ---------------------------------------------------------------------------
// Kernel 4: z2 = bf16( silu( zpre + msg @ Wh_w1[128:256] ) ) (r8, frozen).
// ---------------------------------------------------------------------------
__global__ void __launch_bounds__(512) k_h1b2(
    const unsigned short* __restrict__ msg, const unsigned short* __restrict__ zpre,
    const float* __restrict__ Wh_w1, unsigned short* __restrict__ z2, int N)
{
  __shared__ unsigned short Wt[128 * 136];     // 34816 B
  __shared__ unsigned short OutS[128 * 136];   // 34816 B -> total 69632 B

  for (int i = threadIdx.x; i < 128 * 128; i += 512){
    int k = i >> 7, col = i & 127;
    Wt[col * 136 + k] = f2b(Wh_w1[(128 + k) * 128 + col]);
  }
  __syncthreads();

  const int lane = threadIdx.x & 63, w = threadIdx.x >> 6;   // w = 0..7
  const int m = lane & 15, q = lane >> 4;

  const int ntiles = (N + 127) >> 7;
  for (int tile = blockIdx.x; tile < ntiles; tile += gridDim.x){
    const int n0 = tile << 7;
    const int n = min(n0 + w * 16 + m, N - 1);

    short8 a[4];
    #pragma unroll
    for (int step = 0; step < 4; ++step)
      a[step] = *(const short8*)(msg + (size_t)n * 128 + step * 32 + q * 8);

    float4v acc[8];
    #pragma unroll
    for (int t = 0; t < 8; ++t) acc[t] = (float4v){0.f, 0.f, 0.f, 0.f};
    #pragma unroll
    for (int step = 0; step < 4; ++step){
      #pragma unroll
      for (int t = 0; t < 8; ++t){
        short8 b = *(const short8*)(Wt + (size_t)(t * 16 + m) * 136 + step * 32 + q * 8);
        acc[t] = __builtin_amdgcn_mfma_f32_16x16x32_bf16(a[step], b, acc[t], 0, 0, 0);
      }
    }

    #pragma unroll
    for (int t = 0; t < 8; ++t)
      #pragma unroll
      for (int r = 0; r < 4; ++r)
        OutS[(w * 16 + q * 4 + r) * 136 + t * 16 + m] = f2b(acc[t][r]);
    __syncthreads();
    for (int i = threadIdx.x; i < 128 * 16; i += 512){
      int node = i >> 4, seg = i & 15;
      int nn = n0 + node;
      if (nn < N){
        uint4 dv = *(const uint4*)(OutS + node * 136 + seg * 8);
        uint4 zv = *(const uint4*)(zpre + (size_t)nn * 128 + seg * 8);
        float fd[8], fz[8];
        unp8(dv, fd); unp8(zv, fz);
        uint4 ov;
        ov.x = packbf(siluf(fz[0] + fd[0]), siluf(fz[1] + fd[1]));
        ov.y = packbf(siluf(fz[2] + fd[2]), siluf(fz[3] + fd[3]));
        ov.z = packbf(siluf(fz[4] + fd[4]), siluf(fz[5] + fd[5]));
        ov.w = packbf(siluf(fz[6] + fd[6]), siluf(fz[7] + fd[7]));
        *(uint4*)(z2 + (size_t)nn * 128 + seg * 8) = ov;
      }
    }
    __syncthreads();
  }
}

// ---------------------------------------------------------------------------
// Kernel 5: hout = h + z2 @ Wh_w2 + Wh_b2 (r8 direct-epilogue, frozen).
// ---------------------------------------------------------------------------
__global__ void __launch_bounds__(256) k_h22(
    const float* __restrict__ h, const unsigned short* __restrict__ z2,
    const float* __restrict__ Wh_w2, const float* __restrict__ Wh_b2,
    float* __restrict__ hout, int N)
{
  __shared__ unsigned short Wt[128 * 136];     // 34816 B only

  for (int i = threadIdx.x; i < 128 * 128; i += 256){
    int k = i >> 7, col = i & 127;
    Wt[col * 136 + k] = f2b(Wh_w2[k * 128 + col]);
  }
  __syncthreads();

  const int lane = threadIdx.x & 63, w = threadIdx.x >> 6;
  const int m = lane & 15, q = lane >> 4;
  float bb[8];
  #pragma unroll
  for (int t = 0; t < 8; ++t) bb[t] = Wh_b2[t * 16 + m];

  const int ntiles = (N + 63) >> 6;
  for (int tile = blockIdx.x; tile < ntiles; tile += gridDim.x){
    const int n0 = tile << 6;
    const int n = min(n0 + w * 16 + m, N - 1);

    short8 a[4];
    #pragma unroll
    for (int step = 0; step < 4; ++step)
      a[step] = *(const short8*)(z2 + (size_t)n * 128 + step * 32 + q * 8);

    float4v acc[8];
    #pragma unroll
    for (int t = 0; t < 8; ++t) acc[t] = (float4v){0.f, 0.f, 0.f, 0.f};
    #pragma unroll
    for (int step = 0; step < 4; ++step){
      #pragma unroll
      for (int t = 0; t < 8; ++t){
        short8 b = *(const short8*)(Wt + (size_t)(t * 16 + m) * 136 + step * 32 + q * 8);
        acc[t] = __builtin_amdgcn_mfma_f32_16x16x32_bf16(a[step], b, acc[t], 0, 0, 0);
      }
    }

    // direct epilogue: lane (m,q) owns nodes n0 + w*16 + q*4 + r, feature t*16+m
    #pragma unroll
    for (int r = 0; r < 4; ++r){
      const int nn = n0 + w * 16 + q * 4 + r;
      if (nn < N){
        const size_t base = (size_t)nn * 128 + m;
        #pragma unroll
        for (int t = 0; t < 8; ++t)
          hout[base + t * 16] = h[base + t * 16] + acc[t][r] + bb[t];
      }
    }
  }
}

extern "C" void kernel_launch(void* const* d_in, const int* in_sizes, int n_in,
                              void* d_out, int out_size, void* d_ws, size_t ws_size,
                              hipStream_t stream)
{
  const float* h      = (const float*)d_in[0];
  const float* x      = (const float*)d_in[1];
  const int*   ei     = (const int*)  d_in[2];
  const float* ea     = (const float*)d_in[3];
  const float* t_emb  = (const float*)d_in[4];
  const float* We_w1  = (const float*)d_in[5];
  const float* We_b1  = (const float*)d_in[6];
  const float* We_w2  = (const float*)d_in[7];
  const float* We_b2  = (const float*)d_in[8];
  const float* Watt_w = (const float*)d_in[9];
  const float* Watt_b = (const float*)d_in[10];
  const float* Wx_w1  = (const float*)d_in[11];
  const float* Wx_b1  = (const float*)d_in[12];
  const float* Wx_w2  = (const float*)d_in[13];
  const float* Wx_b2  = (const float*)d_in[14];
  const float* Wx_w3  = (const float*)d_in[15];
  const float* Wh_w1  = (const float*)d_in[16];
  const float* Wh_b1  = (const float*)d_in[17];
  const float* Wh_w2  = (const float*)d_in[18];
  const float* Wh_b2  = (const float*)d_in[19];

  const int N = in_sizes[0] / HD;
  const int E = in_sizes[2] / 2;

  char* ws = (char*)d_ws;
  unsigned short* Aes  = (unsigned short*)ws;  ws += (size_t)N * HD * 2;
  unsigned short* Aed  = (unsigned short*)ws;  ws += (size_t)N * HD * 2;
  unsigned short* Axs  = (unsigned short*)ws;  ws += (size_t)N * HD * 2;
  unsigned short* Axd  = (unsigned short*)ws;  ws += (size_t)N * HD * 2;
  unsigned short* zpre = (unsigned short*)ws;  ws += (size_t)N * HD * 2;
  unsigned short* z2   = (unsigned short*)ws;  ws += (size_t)N * HD * 2;
  unsigned short* msg_agg = (unsigned short*)ws; ws += (size_t)N * HD * 2;
  unsigned short* hb   = (unsigned short*)ws;  ws += (size_t)N * HD * 2;
  unsigned short* tb   = (unsigned short*)ws;  ws += (size_t)N * TD * 2;

  // Overlays into [hb .. hb+16MB) AFTER k_pre2 consumed hb/tb:
  //   ss (E ints) | ddv (E ints) | daux (E float4) = 24E = 14.4MB <= 16MB
  char* sortbase = (char*)hb;
  int*    ss_   = (int*)sortbase;
  int*    ddv_  = ss_ + E;
  float4* daux_ = (float4*)(sortbase + (size_t)8 * E);
  // cnt/off live in msg_agg's first 2N ints during sort (re-zeroed after)
  int* cnt_ = (int*)msg_agg;
  int* off_ = cnt_ + N;

  float* hout = (float*)d_out;
  float* xout = hout + (size_t)N * HD;
  // eaS (E x 16 bf16, sorted order) borrows hout space; k_h22 (last kernel)
  // fully overwrites hout afterwards. Stream order guarantees safety.
  unsigned short* eaS_ = (unsigned short*)hout;

  hipMemsetAsync(msg_agg, 0, (size_t)N * HD * 2, stream);   // also zeroes cnt/off
  hipMemcpyAsync(xout, x, (size_t)N * 3 * 4, hipMemcpyDeviceToDevice, stream);

  // fused: h->bf16, t->bf16, dst histogram
  k_prep<<<600, 256, 0, stream>>>(h, t_emb, ei, hb, tb, cnt_,
                                  N * (HD / 8), N * (TD / 8), E);

  dim3 gP(96, 5);
  k_pre2<<<gP, 512, 0, stream>>>(hb, tb, We_w1, We_b1, Wx_w1, Wx_b1,
                                 Wh_w1, Wh_b1, Aes, Aed, Axs, Axd, zpre, N);

  k_scan<<<1, 1024, 0, stream>>>(cnt_, off_, N);
  k_scatter<<<1024, 256, 0, stream>>>(ei, x, ea, off_, ss_, ddv_, daux_, eaS_, E);

  // re-zero the msg_agg area that hosted cnt/off
  hipMemsetAsync(msg_agg, 0, (size_t)2 * N * sizeof(int), stream);

  k_edge_msg<<<512, 512, 0, stream>>>(ss_, ddv_, eaS_, daux_, Aes, Aed,
                                      We_w1, We_w2, We_b2, Watt_w, Watt_b,
                                      msg_agg, E);
  k_edge_coord<<<512, 512, 0, stream>>>(ss_, ddv_, eaS_, daux_, Axs, Axd,
                                        Wx_w1, Wx_w2, Wx_b2, Wx_w3, xout, E);
  k_h1b2<<<256, 512, 0, stream>>>(msg_agg, zpre, Wh_w1, z2, N);
  k_h22<<<768, 256, 0, stream>>>(h, z2, Wh_w2, Wh_b2, hout, N);
}

// Round 10
// 503.426 us; speedup vs baseline: 2.9402x; 1.0203x over previous
//
#include <hip/hip_runtime.h>
#include <hip/hip_bf16.h>

#define HD 128
#define ED 16
#define TD 32

typedef __attribute__((ext_vector_type(8))) short short8;
typedef __attribute__((ext_vector_type(4))) float float4v;

__device__ __forceinline__ float rcpf(float x){ return __builtin_amdgcn_rcpf(x); }
__device__ __forceinline__ float siluf(float v){ return v * rcpf(1.0f + __expf(-v)); }

// bf16 pack/unpack helpers
__device__ __forceinline__ unsigned int bfbits(float x){          // RTNE
  unsigned int a = __float_as_uint(x);
  return (a + 0x7fffu + ((a >> 16) & 1u)) >> 16;
}
__device__ __forceinline__ unsigned int packbf(float lo, float hi){  // RTNE pair
  return (bfbits(lo) & 0xffffu) | (bfbits(hi) << 16);
}
// 1-op truncation pack via v_perm_b32: [lo.b2, lo.b3, hi.b2, hi.b3]
__device__ __forceinline__ unsigned int packtrunc(float lo, float hi){
  return __builtin_amdgcn_perm(__float_as_uint(hi), __float_as_uint(lo), 0x07060302u);
}
__device__ __forceinline__ float unplo(unsigned int w){ return __uint_as_float(w << 16); }
__device__ __forceinline__ float unphi(unsigned int w){ return __uint_as_float(w & 0xffff0000u); }
__device__ __forceinline__ unsigned short f2b(float x){ return (unsigned short)bfbits(x); }

__device__ __forceinline__ void unp8(uint4 u, float* f){
  f[0]=unplo(u.x); f[1]=unphi(u.x); f[2]=unplo(u.y); f[3]=unphi(u.y);
  f[4]=unplo(u.z); f[5]=unphi(u.z); f[6]=unplo(u.w); f[7]=unphi(u.w);
}

__device__ __forceinline__ void atomAddF(float* p, float v){
  unsafeAtomicAdd(p, v);  // HW global_atomic_add_f32 on gfx950
}

// packed bf16 atomic add: one instruction adds 2 bf16 lanes-worth
__device__ __forceinline__ void atomAddBF2(unsigned short* p, unsigned int packed){
  asm volatile("global_atomic_pk_add_bf16 %0, %1, off"
               :: "v"((unsigned long long)(uintptr_t)p), "v"(packed) : "memory");
}

// ---------------------------------------------------------------------------
// Kernel 0 (v10): fused prep — h->bf16, t->bf16, dst histogram,
// msg_agg zeroing, x->xout copy. Replaces 2 memsets + 1 memcpy + 3 kernels.
// (cnt must be pre-zeroed by the single small memset before this kernel.)
// ---------------------------------------------------------------------------
__global__ void __launch_bounds__(256) k_prep(
    const float* __restrict__ h, const float* __restrict__ t_emb,
    const int* __restrict__ ei, const float* __restrict__ x,
    unsigned short* __restrict__ hb, unsigned short* __restrict__ tbuf,
    int* __restrict__ cnt, uint4* __restrict__ msgz, float* __restrict__ xout,
    int nh8, int nt8, int E, int N)
{
  const int i0 = blockIdx.x * 256 + threadIdx.x, st = gridDim.x * 256;
  for (int i = i0; i < nh8; i += st){
    float4 v0 = *(const float4*)(h + (size_t)i * 8);
    float4 v1 = *(const float4*)(h + (size_t)i * 8 + 4);
    uint4 o;
    o.x = packbf(v0.x, v0.y); o.y = packbf(v0.z, v0.w);
    o.z = packbf(v1.x, v1.y); o.w = packbf(v1.z, v1.w);
    *(uint4*)(hb + (size_t)i * 8) = o;
  }
  for (int i = i0; i < nt8; i += st){
    float4 v0 = *(const float4*)(t_emb + (size_t)i * 8);
    float4 v1 = *(const float4*)(t_emb + (size_t)i * 8 + 4);
    uint4 o;
    o.x = packbf(v0.x, v0.y); o.y = packbf(v0.z, v0.w);
    o.z = packbf(v1.x, v1.y); o.w = packbf(v1.z, v1.w);
    *(uint4*)(tbuf + (size_t)i * 8) = o;
  }
  for (int e = i0; e < E; e += st)
    atomicAdd(&cnt[ei[E + e]], 1);
  const uint4 z = {0u, 0u, 0u, 0u};
  const int nz = N * 16;                 // msg_agg = N*128 bf16 = N*16 uint4
  for (int i = i0; i < nz; i += st) msgz[i] = z;
  const int nx = N * 3;
  for (int i = i0; i < nx; i += st) xout[i] = x[i];
}

__global__ void __launch_bounds__(1024) k_scan(
    const int* __restrict__ cnt, int* __restrict__ off, int n)
{
  const int tid = threadIdx.x, lane = tid & 63, wv = tid >> 6;  // 16 waves
  __shared__ int wsum[16];
  __shared__ int carryS;
  if (tid == 0) carryS = 0;
  __syncthreads();
  const int CH = 1024 * 8;
  for (int base = 0; base < n; base += CH){
    const int idx0 = base + tid * 8;
    int v[8];
    #pragma unroll
    for (int j = 0; j < 8; ++j){ int i = idx0 + j; v[j] = (i < n) ? cnt[i] : 0; }
    #pragma unroll
    for (int j = 1; j < 8; ++j) v[j] += v[j - 1];   // local inclusive
    const int tot = v[7];
    int sc = tot;                                    // wave inclusive scan
    #pragma unroll
    for (int d = 1; d < 64; d <<= 1){ int t = __shfl_up(sc, d); if (lane >= d) sc += t; }
    if (lane == 63) wsum[wv] = sc;
    __syncthreads();
    if (tid < 16){
      int s = wsum[tid];
      #pragma unroll
      for (int d = 1; d < 16; d <<= 1){ int t = __shfl_up(s, d); if (tid >= d) s += t; }
      wsum[tid] = s;
    }
    __syncthreads();
    const int base_excl = carryS + (wv > 0 ? wsum[wv - 1] : 0) + (sc - tot);
    #pragma unroll
    for (int j = 0; j < 8; ++j){
      int i = idx0 + j;
      if (i < n) off[i] = base_excl + (j > 0 ? v[j - 1] : 0);
    }
    __syncthreads();
    if (tid == 0) carryS += wsum[15];
    __syncthreads();
  }
}

__global__ void __launch_bounds__(256) k_scatter(
    const int* __restrict__ ei, const float* __restrict__ x,
    const float* __restrict__ ea, int* __restrict__ off,
    int* __restrict__ ss, int* __restrict__ ddv,
    float4* __restrict__ daux, unsigned short* __restrict__ eaS, int E)
{
  for (int e = blockIdx.x * 256 + threadIdx.x; e < E; e += gridDim.x * 256){
    int s = ei[e], d = ei[E + e];
    int pos = atomicAdd(&off[d], 1);
    ss[pos] = s; ddv[pos] = d;
    float dx = x[s * 3 + 0] - x[d * 3 + 0];
    float dy = x[s * 3 + 1] - x[d * 3 + 1];
    float dz = x[s * 3 + 2] - x[d * 3 + 2];
    float4 da; da.x = dx; da.y = dy; da.z = dz; da.w = dx*dx + dy*dy + dz*dz;
    daux[pos] = da;
    const float4* e4 = (const float4*)(ea + (size_t)e * ED);
    float4 a = e4[0], b = e4[1], c = e4[2], dd = e4[3];
    uint4 o1, o2;
    o1.x = packtrunc(a.x, a.y); o1.y = packtrunc(a.z, a.w);
    o1.z = packtrunc(b.x, b.y); o1.w = packtrunc(b.z, b.w);
    o2.x = packtrunc(c.x, c.y); o2.y = packtrunc(c.z, c.w);
    o2.z = packtrunc(dd.x, dd.y); o2.w = packtrunc(dd.z, dd.w);
    *(uint4*)(eaS + (size_t)pos * 16) = o1;
    *(uint4*)(eaS + (size_t)pos * 16 + 8) = o2;
  }
}

// ---------------------------------------------------------------------------
// Kernel 1: node-side first-layer GEMMs via MFMA (r8 structure, frozen).
// ---------------------------------------------------------------------------
__global__ void __launch_bounds__(512) k_pre2(
    const unsigned short* __restrict__ hb, const unsigned short* __restrict__ tb,
    const float* __restrict__ We_w1, const float* __restrict__ We_b1,
    const float* __restrict__ Wx_w1, const float* __restrict__ Wx_b1,
    const float* __restrict__ Wh_w1, const float* __restrict__ Wh_b1,
    unsigned short* __restrict__ Aes, unsigned short* __restrict__ Aed,
    unsigned short* __restrict__ Axs, unsigned short* __restrict__ Axd,
    unsigned short* __restrict__ zpre, int N)
{
  __shared__ unsigned short Wt[128 * 168];     // 43008 B
  __shared__ unsigned short OutS[128 * 136];   // 34816 B -> total 77824 B

  const int group = blockIdx.y;
  const float* Wsrc = (group <= 1) ? We_w1 : (group <= 3) ? Wx_w1 : Wh_w1;
  const float* bias = (group == 0) ? We_b1 : (group == 2) ? Wx_b1
                    : (group == 4) ? Wh_b1 : nullptr;
  unsigned short* out = (group == 0) ? Aes : (group == 1) ? Aed
                      : (group == 2) ? Axs : (group == 3) ? Axd : zpre;
  const int rowBase = (group == 1 || group == 3) ? 128 : 0;
  const int tBase   = (group == 0) ? 273 : (group == 2) ? 272 : -1;

  for (int i = threadIdx.x; i < 160 * 128; i += 512){
    int k = i >> 7, col = i & 127;
    float wv = 0.f;
    if (k < 128)      wv = Wsrc[(rowBase + k) * 128 + col];
    else if (tBase >= 0) wv = Wsrc[(tBase + (k - 128)) * 128 + col];
    Wt[col * 168 + k] = f2b(wv);
  }
  __syncthreads();

  const int lane = threadIdx.x & 63, w = threadIdx.x >> 6;   // w = 0..7
  const int m = lane & 15, q = lane >> 4;
  float bb[8];
  #pragma unroll
  for (int t = 0; t < 8; ++t) bb[t] = bias ? bias[t * 16 + m] : 0.f;

  const int ntiles = (N + 127) >> 7;
  for (int tile = blockIdx.x; tile < ntiles; tile += gridDim.x){
    const int n0 = tile << 7;
    const int n = min(n0 + w * 16 + m, N - 1);

    short8 a[5];
    #pragma unroll
    for (int step = 0; step < 4; ++step)
      a[step] = *(const short8*)(hb + (size_t)n * 128 + step * 32 + q * 8);
    a[4] = *(const short8*)(tb + (size_t)n * 32 + q * 8);

    float4v acc[8];
    #pragma unroll
    for (int t = 0; t < 8; ++t) acc[t] = (float4v){0.f, 0.f, 0.f, 0.f};
    #pragma unroll
    for (int step = 0; step < 5; ++step){
      #pragma unroll
      for (int t = 0; t < 8; ++t){
        short8 b = *(const short8*)(Wt + (size_t)(t * 16 + m) * 168 + step * 32 + q * 8);
        acc[t] = __builtin_amdgcn_mfma_f32_16x16x32_bf16(a[step], b, acc[t], 0, 0, 0);
      }
    }

    #pragma unroll
    for (int t = 0; t < 8; ++t)
      #pragma unroll
      for (int r = 0; r < 4; ++r)
        OutS[(w * 16 + q * 4 + r) * 136 + t * 16 + m] = f2b(acc[t][r] + bb[t]);
    __syncthreads();
    for (int i = threadIdx.x; i < 128 * 16; i += 512){
      int node = i >> 4, seg = i & 15;
      int nn = n0 + node;
      if (nn < N)
        *(uint4*)(out + (size_t)nn * 128 + seg * 8) =
            *(const uint4*)(OutS + node * 136 + seg * 8);
    }
    __syncthreads();
  }
}

// ---------------------------------------------------------------------------
// Kernel 2 (v10): FUSED edge kernel. blockIdx.y==0 -> message path,
// blockIdx.y==1 -> coord path. Both bodies are the r8-proven inner loops.
// One dispatch instead of two; waves of the two paths co-schedule.
// ---------------------------------------------------------------------------
__global__ void __launch_bounds__(512, 4) k_edge(
    const int* __restrict__ ss, const int* __restrict__ ddv,
    const unsigned short* __restrict__ eaS, const float4* __restrict__ daux,
    const unsigned short* __restrict__ Aes, const unsigned short* __restrict__ Aed,
    const unsigned short* __restrict__ Axs, const unsigned short* __restrict__ Axd,
    const float* __restrict__ We_w1, const float* __restrict__ We_w2,
    const float* __restrict__ We_b2, const float* __restrict__ Watt_w,
    const float* __restrict__ Watt_b,
    const float* __restrict__ Wx_w1, const float* __restrict__ Wx_w2,
    const float* __restrict__ Wx_b2, const float* __restrict__ Wx_w3,
    unsigned short* __restrict__ msg_agg, float* __restrict__ xout, int E)
{
  __shared__ __align__(16) unsigned short W2t[128 * 136];   // 34816 B
  __shared__ __align__(16) unsigned short Btl[128 * 24];    // 6144 B
  __shared__ __align__(16) unsigned short Ssh[8][16 * 140]; // 35840 B
  __shared__ __align__(16) float b2l[128];                  // 512 B
  __shared__ __align__(16) float wl[128];                   // 512 B
  // total 77824 B -> 2 blocks/CU (16 waves)

  const bool MSG = (blockIdx.y == 0);
  const int tid = threadIdx.x;

  if (MSG){
    for (int i = tid; i < 128 * 128; i += 512){
      int col = i & 127, k = i >> 7;
      W2t[col * 136 + k] = f2b(We_w2[k * 128 + col]);
    }
    for (int i = tid; i < 128 * 24; i += 512){
      int col = i / 24, k = i % 24;
      float wv = (k < 16) ? We_w1[(257 + k) * 128 + col]
               : (k == 16 ? We_w1[256 * 128 + col] : 0.f);
      Btl[col * 24 + k] = f2b(wv);
    }
    for (int i = tid; i < 128; i += 512){ b2l[i] = We_b2[i]; wl[i] = Watt_w[i]; }
  } else {
    for (int i = tid; i < 128 * 128; i += 512){
      int col = i & 127, k = i >> 7;
      W2t[col * 136 + k] = f2b(Wx_w2[k * 128 + col]);
    }
    for (int i = tid; i < 128 * 24; i += 512){
      int col = i / 24, k = i % 24;
      Btl[col * 24 + k] = f2b(k < 16 ? Wx_w1[(256 + k) * 128 + col] : 0.f);
    }
    for (int i = tid; i < 128; i += 512){ b2l[i] = Wx_b2[i]; wl[i] = Wx_w3[i]; }
  }
  __syncthreads();

  const int lane = tid & 63, w = tid >> 6;
  const int m = lane & 15, q = lane >> 4;
  unsigned short* S = Ssh[w];

  const int tiles = (E + 15) >> 4;
  const int wid = blockIdx.x * 8 + w;
  const int nwv = gridDim.x * 8;

  if (MSG){
    const float attb = Watt_b[0];
    for (int tb = wid; tb < tiles; tb += nwv){
      const int e0 = tb << 4;

      // per-edge indices/scalars (lanes 0..15), distributed via shfl
      int smy = 0, dmy = 0; float dval = 0.f;
      if (lane < 16){
        const int eC = min(e0 + lane, E - 1);
        smy = ss[eC]; dmy = ddv[eC]; dval = daux[eC].w;
      }
      const int s_m = __shfl(smy, m), d_m = __shfl(dmy, m);
      const float dm = __shfl(dval, m);

      // tail B-frag: lane = edge m, k-slice q*8; k<16 = ea, k==16 = dist
      union { short8 v; unsigned int u[4]; } at;
      at.u[0] = at.u[1] = at.u[2] = at.u[3] = 0u;
      if (q < 2){
        at.v = *(const short8*)(eaS + (size_t)min(e0 + m, E - 1) * 16 + q * 8);
      } else if (q == 2){
        at.u[0] = __float_as_uint(dm) >> 16;
      }

      const unsigned short* pS = Aes + (size_t)s_m * HD + q * 4;
      const unsigned short* pD = Aed + (size_t)d_m * HD + q * 4;

      // tail MFMA swapped, 2 phases of 4 t's; C = f32 sum of gathers; silu->S
      #pragma unroll
      for (int ph = 0; ph < 2; ++ph){
        uint2 gs[4], gd[4];
        #pragma unroll
        for (int j = 0; j < 4; ++j){
          gs[j] = *(const uint2*)(pS + (ph * 4 + j) * 16);
          gd[j] = *(const uint2*)(pD + (ph * 4 + j) * 16);
        }
        #pragma unroll
        for (int j = 0; j < 4; ++j){
          const int t = ph * 4 + j;
          float4v ci;
          ci[0] = unplo(gs[j].x) + unplo(gd[j].x);
          ci[1] = unphi(gs[j].x) + unphi(gd[j].x);
          ci[2] = unplo(gs[j].y) + unplo(gd[j].y);
          ci[3] = unphi(gs[j].y) + unphi(gd[j].y);
          short8 aB;
          if (q < 3) aB = *(const short8*)(Btl + (t * 16 + m) * 24 + q * 8);
          else { union { short8 v; unsigned int u[4]; } z; z.u[0]=z.u[1]=z.u[2]=z.u[3]=0u; aB = z.v; }
          float4v o = __builtin_amdgcn_mfma_f32_16x16x32_bf16(aB, at.v, ci, 0, 0, 0);
          uint2 ov;
          ov.x = packtrunc(siluf(o[0]), siluf(o[1]));
          ov.y = packtrunc(siluf(o[2]), siluf(o[3]));
          *(uint2*)(S + m * 140 + t * 16 + q * 4) = ov;
        }
      }

      // layer-2 MFMA swapped: A = W2^T from LDS, B = u^T from S
      float4v c2[8];
      #pragma unroll
      for (int t = 0; t < 8; ++t) c2[t] = (float4v){0.f, 0.f, 0.f, 0.f};
      #pragma unroll
      for (int step = 0; step < 4; ++step){
        short8 bU = *(const short8*)(S + m * 140 + step * 32 + q * 8);
        #pragma unroll
        for (int t = 0; t < 8; ++t){
          short8 aW = *(const short8*)(W2t + (size_t)(t * 16 + m) * 136 + step * 32 + q * 8);
          c2[t] = __builtin_amdgcn_mfma_f32_16x16x32_bf16(aW, bU, c2[t], 0, 0, 0);
        }
      }

      // attention: lane holds edge m's n-values; 1 sigmoid/lane, 2-shfl reduce
      float p = 0.f;
      #pragma unroll
      for (int t = 0; t < 8; ++t){
        float4 bv = *(const float4*)(b2l + t * 16 + q * 4);
        float4 wv = *(const float4*)(wl + t * 16 + q * 4);
        c2[t][0] += bv.x; c2[t][1] += bv.y; c2[t][2] += bv.z; c2[t][3] += bv.w;
        p = fmaf(c2[t][0], wv.x, p); p = fmaf(c2[t][1], wv.y, p);
        p = fmaf(c2[t][2], wv.z, p); p = fmaf(c2[t][3], wv.w, p);
      }
      p += __shfl_xor(p, 16); p += __shfl_xor(p, 32);
      const float att = rcpf(1.f + __expf(-(p + attb)));
      #pragma unroll
      for (int t = 0; t < 8; ++t){
        uint2 ov;
        ov.x = packtrunc(att * c2[t][0], att * c2[t][1]);
        ov.y = packtrunc(att * c2[t][2], att * c2[t][3]);
        *(uint2*)(S + m * 140 + t * 16 + q * 4) = ov;
      }

      // segmented f32 reduction over sorted dsts; one pk atomic per run
      __builtin_amdgcn_sched_barrier(0);
      float a0 = 0.f, a1 = 0.f;
      int dp = __shfl(dmy, 0);
      #pragma unroll
      for (int half = 0; half < 2; ++half){
        unsigned int vv[8]; int dvr[8];
        #pragma unroll
        for (int j = 0; j < 8; ++j){
          const int eg = half * 8 + j;
          vv[j]  = *(const unsigned int*)(S + eg * 140 + lane * 2);
          dvr[j] = __shfl(dmy, eg);
        }
        #pragma unroll
        for (int j = 0; j < 8; ++j){
          if (dvr[j] != dp){                      // wave-uniform branch
            atomAddBF2(msg_agg + (size_t)dp * HD + lane * 2, packbf(a0, a1));
            a0 = a1 = 0.f; dp = dvr[j];
          }
          if (e0 + half * 8 + j < E){ a0 += unplo(vv[j]); a1 += unphi(vv[j]); }
        }
      }
      atomAddBF2(msg_agg + (size_t)dp * HD + lane * 2, packbf(a0, a1));
    }
  } else {
    for (int tb = wid; tb < tiles; tb += nwv){
      const int e0 = tb << 4;

      int smy = 0, dmy = 0;
      float dxv = 0.f, dyv = 0.f, dzv = 0.f, rsv = 0.f;
      if (lane < 16){
        const int eC = min(e0 + lane, E - 1);
        smy = ss[eC]; dmy = ddv[eC];
        float4 d4 = daux[eC];
        dxv = d4.x; dyv = d4.y; dzv = d4.z;
        rsv = 2.5f * rcpf(sqrtf(d4.w + 1e-8f) + 1.0f);
      }
      const int s_m = __shfl(smy, m), d_m = __shfl(dmy, m);
      const float dxm = __shfl(dxv, m), dym = __shfl(dyv, m);
      const float dzm = __shfl(dzv, m), rsm = __shfl(rsv, m);

      // tail B-frag (ea only, k<16)
      union { short8 v; unsigned int u[4]; } at;
      at.u[0] = at.u[1] = at.u[2] = at.u[3] = 0u;
      if (q < 2)
        at.v = *(const short8*)(eaS + (size_t)min(e0 + m, E - 1) * 16 + q * 8);

      const unsigned short* pS = Axs + (size_t)s_m * HD + q * 4;
      const unsigned short* pD = Axd + (size_t)d_m * HD + q * 4;

      #pragma unroll
      for (int ph = 0; ph < 2; ++ph){
        uint2 gs[4], gd[4];
        #pragma unroll
        for (int j = 0; j < 4; ++j){
          gs[j] = *(const uint2*)(pS + (ph * 4 + j) * 16);
          gd[j] = *(const uint2*)(pD + (ph * 4 + j) * 16);
        }
        #pragma unroll
        for (int j = 0; j < 4; ++j){
          const int t = ph * 4 + j;
          float4v ci;
          ci[0] = unplo(gs[j].x) + unplo(gd[j].x);
          ci[1] = unphi(gs[j].x) + unphi(gd[j].x);
          ci[2] = unplo(gs[j].y) + unplo(gd[j].y);
          ci[3] = unphi(gs[j].y) + unphi(gd[j].y);
          short8 aB;
          if (q < 2) aB = *(const short8*)(Btl + (t * 16 + m) * 24 + q * 8);
          else { union { short8 v; unsigned int u[4]; } z; z.u[0]=z.u[1]=z.u[2]=z.u[3]=0u; aB = z.v; }
          float4v o = __builtin_amdgcn_mfma_f32_16x16x32_bf16(aB, at.v, ci, 0, 0, 0);
          uint2 ov;
          ov.x = packtrunc(siluf(o[0]), siluf(o[1]));
          ov.y = packtrunc(siluf(o[2]), siluf(o[3]));
          *(uint2*)(S + m * 140 + t * 16 + q * 4) = ov;
        }
      }

      float4v c2[8];
      #pragma unroll
      for (int t = 0; t < 8; ++t) c2[t] = (float4v){0.f, 0.f, 0.f, 0.f};
      #pragma unroll
      for (int step = 0; step < 4; ++step){
        short8 bU = *(const short8*)(S + m * 140 + step * 32 + q * 8);
        #pragma unroll
        for (int t = 0; t < 8; ++t){
          short8 aW = *(const short8*)(W2t + (size_t)(t * 16 + m) * 136 + step * 32 + q * 8);
          c2[t] = __builtin_amdgcn_mfma_f32_16x16x32_bf16(aW, bU, c2[t], 0, 0, 0);
        }
      }

      // coord weight: lane holds edge m; 1 tanh/lane via exp+rcp
      float p = 0.f;
      #pragma unroll
      for (int t = 0; t < 8; ++t){
        float4 bv = *(const float4*)(b2l + t * 16 + q * 4);
        float4 wv = *(const float4*)(wl + t * 16 + q * 4);
        p = fmaf(siluf(c2[t][0] + bv.x), wv.x, p);
        p = fmaf(siluf(c2[t][1] + bv.y), wv.y, p);
        p = fmaf(siluf(c2[t][2] + bv.z), wv.z, p);
        p = fmaf(siluf(c2[t][3] + bv.w), wv.w, p);
      }
      p += __shfl_xor(p, 16); p += __shfl_xor(p, 32);
      const float th = 1.f - 2.f * rcpf(1.f + __expf(2.f * p));  // tanh(p)
      const float sc = th * rsm;
      const float comp = (q == 0) ? dxm : (q == 1) ? dym : dzm;
      const float contrib = comp * sc;   // meaningful for q<3

      // segmented emit: lanes 0..2 emit; contributions pulled via shfl
      __builtin_amdgcn_sched_barrier(0);
      int dp = __shfl(dmy, 0); float acc = 0.f;
      #pragma unroll
      for (int eg = 0; eg < 16; ++eg){
        int dc = __shfl(dmy, eg);
        float c = __shfl(contrib, ((lane & 3) << 4) + eg);
        if (dc != dp){                               // wave-uniform
          if (lane < 3) atomAddF(xout + (size_t)dp * 3 + lane, acc);
          acc = 0.f; dp = dc;
        }
        if (e0 + eg < E) acc += c;
      }
      if (lane < 3) atomAddF(xout + (size_t)dp * 3 + lane, acc);
    }
  }
}

// ---------------------------------------------------------------------------
// Kernel 4: z2 = bf16( silu( zpre + msg @ Wh_w1[128:256] ) ) (r8, frozen).
// ---------------------------------------------------------------------------
__global__ void __launch_bounds__(512) k_h1b2(
    const unsigned short* __restrict__ msg, const unsigned short* __restrict__ zpre,
    const float* __restrict__ Wh_w1, unsigned short* __restrict__ z2, int N)
{
  __shared__ unsigned short Wt[128 * 136];     // 34816 B
  __shared__ unsigned short OutS[128 * 136];   // 34816 B -> total 69632 B

  for (int i = threadIdx.x; i < 128 * 128; i += 512){
    int k = i >> 7, col = i & 127;
    Wt[col * 136 + k] = f2b(Wh_w1[(128 + k) * 128 + col]);
  }
  __syncthreads();

  const int lane = threadIdx.x & 63, w = threadIdx.x >> 6;   // w = 0..7
  const int m = lane & 15, q = lane >> 4;

  const int ntiles = (N + 127) >> 7;
  for (int tile = blockIdx.x; tile < ntiles; tile += gridDim.x){
    const int n0 = tile << 7;
    const int n = min(n0 + w * 16 + m, N - 1);

    short8 a[4];
    #pragma unroll
    for (int step = 0; step < 4; ++step)
      a[step] = *(const short8*)(msg + (size_t)n * 128 + step * 32 + q * 8);

    float4v acc[8];
    #pragma unroll
    for (int t = 0; t < 8; ++t) acc[t] = (float4v){0.f, 0.f, 0.f, 0.f};
    #pragma unroll
    for (int step = 0; step < 4; ++step){
      #pragma unroll
      for (int t = 0; t < 8; ++t){
        short8 b = *(const short8*)(Wt + (size_t)(t * 16 + m) * 136 + step * 32 + q * 8);
        acc[t] = __builtin_amdgcn_mfma_f32_16x16x32_bf16(a[step], b, acc[t], 0, 0, 0);
      }
    }

    #pragma unroll
    for (int t = 0; t < 8; ++t)
      #pragma unroll
      for (int r = 0; r < 4; ++r)
        OutS[(w * 16 + q * 4 + r) * 136 + t * 16 + m] = f2b(acc[t][r]);
    __syncthreads();
    for (int i = threadIdx.x; i < 128 * 16; i += 512){
      int node = i >> 4, seg = i & 15;
      int nn = n0 + node;
      if (nn < N){
        uint4 dv = *(const uint4*)(OutS + node * 136 + seg * 8);
        uint4 zv = *(const uint4*)(zpre + (size_t)nn * 128 + seg * 8);
        float fd[8], fz[8];
        unp8(dv, fd); unp8(zv, fz);
        uint4 ov;
        ov.x = packbf(siluf(fz[0] + fd[0]), siluf(fz[1] + fd[1]));
        ov.y = packbf(siluf(fz[2] + fd[2]), siluf(fz[3] + fd[3]));
        ov.z = packbf(siluf(fz[4] + fd[4]), siluf(fz[5] + fd[5]));
        ov.w = packbf(siluf(fz[6] + fd[6]), siluf(fz[7] + fd[7]));
        *(uint4*)(z2 + (size_t)nn * 128 + seg * 8) = ov;
      }
    }
    __syncthreads();
  }
}

// ---------------------------------------------------------------------------
// Kernel 5: hout = h + z2 @ Wh_w2 + Wh_b2 (r8 direct-epilogue, frozen).
// ---------------------------------------------------------------------------
__global__ void __launch_bounds__(256) k_h22(
    const float* __restrict__ h, const unsigned short* __restrict__ z2,
    const float* __restrict__ Wh_w2, const float* __restrict__ Wh_b2,
    float* __restrict__ hout, int N)
{
  __shared__ unsigned short Wt[128 * 136];     // 34816 B only

  for (int i = threadIdx.x; i < 128 * 128; i += 256){
    int k = i >> 7, col = i & 127;
    Wt[col * 136 + k] = f2b(Wh_w2[k * 128 + col]);
  }
  __syncthreads();

  const int lane = threadIdx.x & 63, w = threadIdx.x >> 6;
  const int m = lane & 15, q = lane >> 4;
  float bb[8];
  #pragma unroll
  for (int t = 0; t < 8; ++t) bb[t] = Wh_b2[t * 16 + m];

  const int ntiles = (N + 63) >> 6;
  for (int tile = blockIdx.x; tile < ntiles; tile += gridDim.x){
    const int n0 = tile << 6;
    const int n = min(n0 + w * 16 + m, N - 1);

    short8 a[4];
    #pragma unroll
    for (int step = 0; step < 4; ++step)
      a[step] = *(const short8*)(z2 + (size_t)n * 128 + step * 32 + q * 8);

    float4v acc[8];
    #pragma unroll
    for (int t = 0; t < 8; ++t) acc[t] = (float4v){0.f, 0.f, 0.f, 0.f};
    #pragma unroll
    for (int step = 0; step < 4; ++step){
      #pragma unroll
      for (int t = 0; t < 8; ++t){
        short8 b = *(const short8*)(Wt + (size_t)(t * 16 + m) * 136 + step * 32 + q * 8);
        acc[t] = __builtin_amdgcn_mfma_f32_16x16x32_bf16(a[step], b, acc[t], 0, 0, 0);
      }
    }

    // direct epilogue: lane (m,q) owns nodes n0 + w*16 + q*4 + r, feature t*16+m
    #pragma unroll
    for (int r = 0; r < 4; ++r){
      const int nn = n0 + w * 16 + q * 4 + r;
      if (nn < N){
        const size_t base = (size_t)nn * 128 + m;
        #pragma unroll
        for (int t = 0; t < 8; ++t)
          hout[base + t * 16] = h[base + t * 16] + acc[t][r] + bb[t];
      }
    }
  }
}

extern "C" void kernel_launch(void* const* d_in, const int* in_sizes, int n_in,
                              void* d_out, int out_size, void* d_ws, size_t ws_size,
                              hipStream_t stream)
{
  const float* h      = (const float*)d_in[0];
  const float* x      = (const float*)d_in[1];
  const int*   ei     = (const int*)  d_in[2];
  const float* ea     = (const float*)d_in[3];
  const float* t_emb  = (const float*)d_in[4];
  const float* We_w1  = (const float*)d_in[5];
  const float* We_b1  = (const float*)d_in[6];
  const float* We_w2  = (const float*)d_in[7];
  const float* We_b2  = (const float*)d_in[8];
  const float* Watt_w = (const float*)d_in[9];
  const float* Watt_b = (const float*)d_in[10];
  const float* Wx_w1  = (const float*)d_in[11];
  const float* Wx_b1  = (const float*)d_in[12];
  const float* Wx_w2  = (const float*)d_in[13];
  const float* Wx_b2  = (const float*)d_in[14];
  const float* Wx_w3  = (const float*)d_in[15];
  const float* Wh_w1  = (const float*)d_in[16];
  const float* Wh_b1  = (const float*)d_in[17];
  const float* Wh_w2  = (const float*)d_in[18];
  const float* Wh_b2  = (const float*)d_in[19];

  const int N = in_sizes[0] / HD;
  const int E = in_sizes[2] / 2;

  char* ws = (char*)d_ws;
  unsigned short* Aes  = (unsigned short*)ws;  ws += (size_t)N * HD * 2;
  unsigned short* Aed  = (unsigned short*)ws;  ws += (size_t)N * HD * 2;
  unsigned short* Axs  = (unsigned short*)ws;  ws += (size_t)N * HD * 2;
  unsigned short* Axd  = (unsigned short*)ws;  ws += (size_t)N * HD * 2;
  unsigned short* zpre = (unsigned short*)ws;  ws += (size_t)N * HD * 2;
  unsigned short* z2   = (unsigned short*)ws;  ws += (size_t)N * HD * 2;
  unsigned short* msg_agg = (unsigned short*)ws; ws += (size_t)N * HD * 2;
  unsigned short* hb   = (unsigned short*)ws;  ws += (size_t)N * HD * 2;
  unsigned short* tb   = (unsigned short*)ws;  ws += (size_t)N * TD * 2;

  // Overlays into [hb .. hb+16MB) AFTER k_pre2 consumed hb/tb:
  //   ss (E ints) | ddv (E ints) | daux (E float4) = 24E = 14.4MB <= 16MB
  char* sortbase = (char*)hb;
  int*    ss_   = (int*)sortbase;
  int*    ddv_  = ss_ + E;
  float4* daux_ = (float4*)(sortbase + (size_t)8 * E);
  // cnt/off live in z2's first 2N ints (z2 is only written later by k_h1b2)
  int* cnt_ = (int*)z2;
  int* off_ = cnt_ + N;

  float* hout = (float*)d_out;
  float* xout = hout + (size_t)N * HD;
  // eaS (E x 16 bf16, sorted order) borrows hout space; k_h22 (last kernel)
  // fully overwrites hout afterwards. Stream order guarantees safety.
  unsigned short* eaS_ = (unsigned short*)hout;

  // single small memset: histogram counters only (cnt in z2 region)
  hipMemsetAsync(cnt_, 0, (size_t)N * sizeof(int), stream);

  // fused: h->bf16, t->bf16, dst histogram, msg_agg zero, x->xout copy
  k_prep<<<600, 256, 0, stream>>>(h, t_emb, ei, x, hb, tb, cnt_,
                                  (uint4*)msg_agg, xout,
                                  N * (HD / 8), N * (TD / 8), E, N);

  dim3 gP(96, 5);
  k_pre2<<<gP, 512, 0, stream>>>(hb, tb, We_w1, We_b1, Wx_w1, Wx_b1,
                                 Wh_w1, Wh_b1, Aes, Aed, Axs, Axd, zpre, N);

  k_scan<<<1, 1024, 0, stream>>>(cnt_, off_, N);
  k_scatter<<<1024, 256, 0, stream>>>(ei, x, ea, off_, ss_, ddv_, daux_, eaS_, E);

  // fused edge kernel: y=0 message path, y=1 coord path
  dim3 gE(512, 2);
  k_edge<<<gE, 512, 0, stream>>>(ss_, ddv_, eaS_, daux_, Aes, Aed, Axs, Axd,
                                 We_w1, We_w2, We_b2, Watt_w, Watt_b,
                                 Wx_w1, Wx_w2, Wx_b2, Wx_w3,
                                 msg_agg, xout, E);

  k_h1b2<<<256, 512, 0, stream>>>(msg_agg, zpre, Wh_w1, z2, N);
  k_h22<<<768, 256, 0, stream>>>(h, z2, Wh_w2, Wh_b2, hout, N);
}